// Round 8
// baseline (599.627 us; speedup 1.0000x reference)
//
#include <hip/hip_runtime.h>
#include <cstddef>
#include <cstdint>

#define BN    32768   // B*N
#define NG    4096    // nodes per graph
#define KNN   24
#define KPW   14      // per-lane partial top over its 1/8 candidate subset
#define KM    32      // merged candidate pool for exact refine
#define CHK   128     // candidates per chunk
#define NBQ   64      // queries per knn block
#define STKD  16      // pending-stack depth per lane
#define TRIG  13      // flush trigger: pcnt<=12 pre-tile, +4 writes at slots<=15

#define AB_FLAG_OFF   28835840   // one-shot ablation flag (after Bbuf)
#define AB_SCR_OFF    28901376   // 128KB ablation scratch
#define AB_END        29032448
#define AB_MAGIC      0xC0FFEEu

typedef float f32x4_t __attribute__((ext_vector_type(4)));
typedef short s16x8_t __attribute__((ext_vector_type(8)));

__device__ __forceinline__ float elu_f(float x) {
    return x > 0.f ? x : expm1f(x);
}

__device__ __forceinline__ unsigned short f2bf(float f) {
    unsigned u = __float_as_uint(f);
    unsigned r = (u + 0x7FFFu + ((u >> 16) & 1u)) >> 16;   // RNE
    return (unsigned short)r;
}

__device__ __forceinline__ void gload_lds16(const void* g, void* l) {
    __builtin_amdgcn_global_load_lds(
        (const __attribute__((address_space(1))) unsigned*)g,
        (__attribute__((address_space(3))) unsigned*)l, 16, 0, 0);
}

// pack one node's 32 features: bf16 linear, bf16 MFMA-A-tiled, bf16-consistent d2
__device__ __forceinline__ void pack_node(int n, const float* hv,
    unsigned short* __restrict__ hbf, unsigned short* __restrict__ til,
    float* __restrict__ d2b)
{
    __align__(16) unsigned short us[32];
    float s = 0.f;
#pragma unroll
    for (int k = 0; k < 32; ++k) {
        us[k] = f2bf(hv[k]);
        float v = __uint_as_float(((unsigned)us[k]) << 16);
        s = fmaf(v, v, s);
    }
    d2b[n] = s;
    const uint4* up = reinterpret_cast<const uint4*>(us);
    uint4* lp = reinterpret_cast<uint4*>(hbf + (size_t)n * 32);
#pragma unroll
    for (int j = 0; j < 4; ++j) lp[j] = up[j];
    const int g = n >> 12, ln = n & 4095, tile = ln >> 4, c = ln & 15;
    unsigned short* tb = til + (size_t)g * 131072 + tile * 512 + c * 8;
#pragma unroll
    for (int kg = 0; kg < 4; ++kg)
        *reinterpret_cast<uint4*>(tb + kg * 128) = up[kg];
}

// ---------------- encoder: x[BN,4] -> h[BN,32] (+bf16 pack, d2, d2b) ----------------
// 256 blocks x 128 threads: one block per CU (all 256 CUs active)
__global__ __launch_bounds__(128) void k_encoder(
    const float* __restrict__ x,
    const float* __restrict__ w1, const float* __restrict__ b1,
    const float* __restrict__ w2, const float* __restrict__ b2,
    float* __restrict__ hOut, float* __restrict__ d2Out,
    unsigned short* __restrict__ hbf, unsigned short* __restrict__ til,
    float* __restrict__ d2b)
{
    __shared__ float sw1[4 * 32];
    __shared__ float sb1[32];
    __shared__ float sw2[32 * 32];
    __shared__ float sb2[32];
    int tid = threadIdx.x;
    sw1[tid] = w1[tid];                     // 128 threads, 128 entries
    if (tid < 32) sb1[tid] = b1[tid];
    for (int i = tid; i < 1024; i += 128) sw2[i] = w2[i];
    if (tid >= 32 && tid < 64) sb2[tid - 32] = b2[tid - 32];
    __syncthreads();

    int node = blockIdx.x * 128 + tid;
    float4 xv = reinterpret_cast<const float4*>(x)[node];

    float h1[32];
#pragma unroll
    for (int o = 0; o < 32; ++o) {
        float s = sb1[o];
        s = fmaf(xv.x, sw1[o], s);
        s = fmaf(xv.y, sw1[32 + o], s);
        s = fmaf(xv.z, sw1[64 + o], s);
        s = fmaf(xv.w, sw1[96 + o], s);
        h1[o] = elu_f(s);
    }
    float h2[32];
    float d2 = 0.f;
#pragma unroll
    for (int o = 0; o < 32; ++o) {
        float s = sb2[o];
#pragma unroll
        for (int f = 0; f < 32; ++f) s = fmaf(h1[f], sw2[f * 32 + o], s);
        float v = elu_f(s);
        h2[o] = v;
        d2 = fmaf(v, v, d2);
    }
    float4* hp = reinterpret_cast<float4*>(hOut) + (size_t)node * 8;
#pragma unroll
    for (int j = 0; j < 8; ++j)
        hp[j] = make_float4(h2[4 * j], h2[4 * j + 1], h2[4 * j + 2], h2[4 * j + 3]);
    d2Out[node] = d2;
    pack_node(node, h2, hbf, til, d2b);
}

// sorted-ascending chain insert into top[KPW]
#define CHAIN14(nk_) do { \
    unsigned nk = (nk_); \
    _Pragma("unroll") \
    for (int jj = 0; jj < KPW; ++jj) { \
        unsigned tj = top[jj]; \
        unsigned lo = nk < tj ? nk : tj; \
        unsigned hi = nk < tj ? tj : nk; \
        top[jj] = lo; nk = hi; \
    } \
} while (0)

// ------------- MFMA kNN + fused precompute (R4 structure, best measured) -------------
__global__ __launch_bounds__(512, 4) void k_knn(
    const unsigned short* __restrict__ til,
    const unsigned short* __restrict__ hbf,
    const float* __restrict__ d2b,
    const float* __restrict__ hf,
    const float* __restrict__ d2x,
    int* __restrict__ idxOut,
    const float* __restrict__ cw, const float* __restrict__ cb,
    float* __restrict__ Abuf, float* __restrict__ Bbuf)
{
    __shared__ __align__(16) unsigned char smem[49152];
    constexpr int SD2 = 0;        // scan: 16KB whole-graph bf16-consistent d2
    constexpr int STK = 16384;    // scan: 8 waves x 4096B pending stacks (16 deep)
    constexpr int LST = 16384;    // epi: sorted lists (reuses stacks after drain)
    constexpr int SW  = 0;        // epi: 2048 f conv weights (reuses d2 region)
    constexpr int SH  = 8192;     // epi: 2048 f block features
    constexpr int MG  = 30720;    // epi: 64 x 32 ids
    constexpr int DSV = 38912;    // epi: 64 x 32 dists
    constexpr int SB  = 47104;    // epi: 32 f bias

    const int tid = threadIdx.x;
    const int lane = tid & 63;
    const int wid = __builtin_amdgcn_readfirstlane(tid >> 6);
    const int qt = wid >> 1;
    const int par = wid & 1;
    const int bid = blockIdx.x;
    const int g = bid >> 6;
    const int gbase = g << 12;
    const int blockq = (bid & 63) * NBQ;
    const int qnode = gbase + blockq + qt * 16 + (lane & 15);
    const int rg = (lane >> 4) * 4;   // candidate row group base within tile

    // stage whole-graph d2 (4096 floats) once: 2 passes x 8 waves x 1KB
    gload_lds16(d2b + gbase + wid * 256 + lane * 4, smem + SD2 + wid * 1024);
    gload_lds16(d2b + gbase + 2048 + wid * 256 + lane * 4,
                smem + SD2 + 8192 + wid * 1024);

    // B fragment: query (lane&15) of this wave's tile, k-slice (lane>>4)*8..+8
    s16x8_t bfrag = *reinterpret_cast<const s16x8_t*>(
        hbf + (size_t)qnode * 32 + (lane >> 4) * 8);
    const float qd2 = d2b[qnode];
    const float nqd2h = -0.5f * qd2;

    unsigned top[KPW];
#pragma unroll
    for (int j = 0; j < KPW; ++j) top[j] = 0xFFFFFFFFu;
    unsigned thresh = 0xFFFFFFFFu;
    int pcnt = 0;

    // this wave's A-fragment stream base: tiles {par, par+2, par+4, par+6}
    const char* gtw = (const char*)til + (size_t)g * 262144
                    + (size_t)par * 1024 + (size_t)lane * 16;
    const float* d2s = reinterpret_cast<const float*>(smem + SD2);
    // per-lane element pointer into this wave's stack: slot j at stkl[j*64]
    unsigned* stkl = reinterpret_cast<unsigned*>(smem + STK + wid * 4096) + lane;

    __syncthreads();   // d2 staged (the ONLY barrier before the epilogue)

    // prologue: prefetch chunk 0 A-fragments into registers
    s16x8_t af[4];
#pragma unroll
    for (int i = 0; i < 4; ++i)
        af[i] = *reinterpret_cast<const s16x8_t*>(gtw + i * 2048);

    for (int c = 0; c < 32; ++c) {
        s16x8_t an[4];
        if (c < 31) {
#pragma unroll
            for (int i = 0; i < 4; ++i)
                an[i] = *reinterpret_cast<const s16x8_t*>(
                    gtw + (size_t)(c + 1) * 8192 + i * 2048);
        } else {
#pragma unroll
            for (int i = 0; i < 4; ++i) an[i] = af[i];
        }
        // candidate d2 for this chunk's 4 tiles (LDS, broadcast within 16 lanes)
        f32x4_t cv[4];
#pragma unroll
        for (int i = 0; i < 4; ++i)
            cv[i] = *reinterpret_cast<const f32x4_t*>(
                d2s + c * 128 + (i * 2 + par) * 16 + rg);
#pragma unroll
        for (int i = 0; i < 4; ++i) {
            const int t = i * 2 + par;
            f32x4_t acc;
#pragma unroll
            for (int r = 0; r < 4; ++r) acc[r] = fmaf(-0.5f, cv[i][r], nqd2h);
            acc = __builtin_amdgcn_mfma_f32_16x16x32_bf16(af[i], bfrag, acc, 0, 0, 0);
            const int cid0 = c * CHK + t * 16 + rg;
#pragma unroll
            for (int r = 0; r < 4; ++r) {
                // acc = -(d/2) <= 0; unsigned-ascending bit pattern == ascending d.
                unsigned key = (__float_as_uint(acc[r]) & 0xFFFFF000u)
                             | (unsigned)(cid0 + r);
                // branchless, exec-free accept
                stkl[pcnt * 64] = key;
                pcnt += (key < thresh) ? 1 : 0;
            }
            if (__any(pcnt >= TRIG)) {
#pragma unroll 1
                for (int j = 0; j < STKD; ++j) {
                    if (!__any(pcnt > j)) break;
                    unsigned kk = stkl[j * 64];                   // uncond read
                    unsigned k = (j < pcnt) ? kk : 0xFFFFFFFFu;   // select
                    CHAIN14(k);
                }
                pcnt = 0;
                thresh = top[KPW - 1];
            }
        }
#pragma unroll
        for (int i = 0; i < 4; ++i) af[i] = an[i];
    }
    // final drain
#pragma unroll 1
    for (int j = 0; j < STKD; ++j) {
        if (!__any(pcnt > j)) break;
        unsigned kk = stkl[j * 64];
        unsigned k = (j < pcnt) ? kk : 0xFFFFFFFFu;
        CHAIN14(k);
    }
    __syncthreads();   // all drains done before list region overwrites stacks

    // dump sorted lists
    unsigned* lst = reinterpret_cast<unsigned*>(smem + LST);
#pragma unroll
    for (int j = 0; j < KPW; ++j) lst[(wid * 64 + lane) * KPW + j] = top[j];
    __syncthreads();

    int* mg = reinterpret_cast<int*>(smem + MG);
    float* dstv = reinterpret_cast<float*>(smem + DSV);

    // P1: per query, merge its 8 sorted lists -> KM candidate ids
    if (tid < NBQ) {
        const int q = tid;
        unsigned mt[KM];
#pragma unroll
        for (int j = 0; j < KM; ++j) mt[j] = 0xFFFFFFFFu;
        for (int li = 0; li < 8; ++li) {
            const unsigned* lk = lst +
                (((q >> 4) * 2 + (li >> 2)) * 64 + (li & 3) * 16 + (q & 15)) * KPW;
            for (int j = 0; j < KPW; ++j) {
                unsigned key = lk[j];
                if (key >= mt[KM - 1]) break;
                unsigned nk = key;
#pragma unroll
                for (int jj = 0; jj < KM; ++jj) {
                    unsigned tj = mt[jj];
                    unsigned lo = nk < tj ? nk : tj;
                    unsigned hi = nk < tj ? tj : nk;
                    mt[jj] = lo; nk = hi;
                }
            }
        }
#pragma unroll
        for (int s = 0; s < KM; ++s) mg[q * 32 + s] = (int)(mt[s] & 0xFFFu);
    }
    __syncthreads();

    // stage precompute weights/features (d2/list regions consumed)
    float* sw = reinterpret_cast<float*>(smem + SW);   // 2048 f
    float* sh = reinterpret_cast<float*>(smem + SH);   // 2048 f
    float* sb = reinterpret_cast<float*>(smem + SB);   // 32 f
    for (int i = tid; i < 2048; i += 512) sw[i] = cw[i];
    for (int i = tid; i < 2048; i += 512)
        sh[i] = hf[(size_t)(gbase + blockq) * 32 + i];
    if (tid < 32) sb[tid] = cb[tid];

    // P2: exact fp32 distances for the KM pool (8 threads/query, 4 cands each)
    {
        const int q = tid >> 3;
        const int s0 = tid & 7;
        const int qn = gbase + blockq + q;
        const float4* qp = reinterpret_cast<const float4*>(hf) + (size_t)qn * 8;
        float4 qf[8];
#pragma unroll
        for (int j = 0; j < 8; ++j) qf[j] = qp[j];
        const float qd2e = d2x[qn];
#pragma unroll
        for (int ss = 0; ss < 4; ++ss) {
            const int s = s0 + ss * 8;
            const int cid = mg[q * 32 + s];
            const int cn = gbase + cid;
            const float4* cp = reinterpret_cast<const float4*>(hf) + (size_t)cn * 8;
            float ax = 0.f, ay = 0.f, az = 0.f, aw = 0.f;
#pragma unroll
            for (int jj = 0; jj < 8; ++jj) {
                float4 cc = cp[jj];
                ax = fmaf(qf[jj].x, cc.x, ax);
                ay = fmaf(qf[jj].y, cc.y, ay);
                az = fmaf(qf[jj].z, cc.z, az);
                aw = fmaf(qf[jj].w, cc.w, aw);
            }
            float dot = (ax + ay) + (az + aw);
            dstv[q * 32 + s] = fmaf(-2.f, dot, qd2e + d2x[cn]);
        }
    }
    __syncthreads();

    // P3: exact top-24 of the KM pool
    if (tid < NBQ) {
        const int q = tid;
        float bd[KNN]; int bi[KNN];
#pragma unroll
        for (int j = 0; j < KNN; ++j) { bd[j] = 1e30f; bi[j] = 0; }
        for (int s = 0; s < KM; ++s) {
            float nd = dstv[q * 32 + s];
            int ni = mg[q * 32 + s];
            if (nd < bd[KNN - 1]) {
#pragma unroll
                for (int jj = 0; jj < KNN; ++jj) {
                    bool lt = nd < bd[jj];
                    float td = bd[jj]; int ti = bi[jj];
                    bd[jj] = lt ? nd : td;
                    bi[jj] = lt ? ni : ti;
                    nd = lt ? td : nd;
                    ni = lt ? ti : ni;
                }
            }
        }
        int* o = idxOut + (size_t)(gbase + blockq + q) * KNN;
#pragma unroll
        for (int j = 0; j < KNN; ++j) o[j] = bi[j];
    }

    // fused precompute for the block's 64 nodes: A = h@(W1-W2)+b, Bv = h@W2
    {
        const int n = tid >> 3;
        const int o0 = (tid & 7) * 4;
        const float* hr = sh + n * 32;
        const int node = gbase + blockq + n;
        float hreg[32];
#pragma unroll
        for (int j = 0; j < 8; ++j) {
            float4 v = *reinterpret_cast<const float4*>(hr + j * 4);
            hreg[4 * j] = v.x; hreg[4 * j + 1] = v.y;
            hreg[4 * j + 2] = v.z; hreg[4 * j + 3] = v.w;
        }
        float4 s1 = make_float4(0.f, 0.f, 0.f, 0.f);
        float4 s2 = make_float4(0.f, 0.f, 0.f, 0.f);
#pragma unroll
        for (int f = 0; f < 32; ++f) {
            float hv = hreg[f];
            float4 wa = *reinterpret_cast<const float4*>(sw + f * 32 + o0);
            float4 wb = *reinterpret_cast<const float4*>(sw + (32 + f) * 32 + o0);
            s1.x = fmaf(hv, wa.x, s1.x); s1.y = fmaf(hv, wa.y, s1.y);
            s1.z = fmaf(hv, wa.z, s1.z); s1.w = fmaf(hv, wa.w, s1.w);
            s2.x = fmaf(hv, wb.x, s2.x); s2.y = fmaf(hv, wb.y, s2.y);
            s2.z = fmaf(hv, wb.z, s2.z); s2.w = fmaf(hv, wb.w, s2.w);
        }
        float4 bv = *reinterpret_cast<const float4*>(sb + o0);
        float4 av = make_float4(s1.x - s2.x + bv.x, s1.y - s2.y + bv.y,
                                s1.z - s2.z + bv.z, s1.w - s2.w + bv.w);
        *reinterpret_cast<float4*>(Abuf + (size_t)node * 32 + o0) = av;
        *reinterpret_cast<float4*>(Bbuf + (size_t)node * 32 + o0) = s2;
    }
}

// ------------- ONE-SHOT ABLATION of the k_knn scan (runs full only on iter 1) -------------
// V=0: staging+MFMA+key (floor).  V=1: +cmp/bump+trigger.  V=2: +stack writes.
// V=3: full selection (chains+drain).  Grid 1024 (2x scan work) so rows outrank
// k_knn in the top-5 dispatch table. Early-exits via device-scope flag.
template <int V>
__global__ __launch_bounds__(512, 4) void k_ablate(
    const unsigned short* __restrict__ til,
    const unsigned short* __restrict__ hbf,
    const float* __restrict__ d2b,
    unsigned* __restrict__ scratch,
    unsigned* __restrict__ flag)
{
    __shared__ __align__(16) unsigned char smem[49152];
    __shared__ unsigned sflag;
    constexpr int SD2 = 0;
    constexpr int STK = 16384;

    const int tid = threadIdx.x;
    if (tid == 0)
        sflag = __hip_atomic_load(flag, __ATOMIC_RELAXED, __HIP_MEMORY_SCOPE_AGENT);
    __syncthreads();
    if (sflag == AB_MAGIC) return;   // armed after first iteration

    const int lane = tid & 63;
    const int wid = __builtin_amdgcn_readfirstlane(tid >> 6);
    const int qt = wid >> 1;
    const int par = wid & 1;
    const int bid = blockIdx.x & 511;
    const int g = bid >> 6;
    const int gbase = g << 12;
    const int blockq = (bid & 63) * NBQ;
    const int qnode = gbase + blockq + qt * 16 + (lane & 15);
    const int rg = (lane >> 4) * 4;

    gload_lds16(d2b + gbase + wid * 256 + lane * 4, smem + SD2 + wid * 1024);
    gload_lds16(d2b + gbase + 2048 + wid * 256 + lane * 4,
                smem + SD2 + 8192 + wid * 1024);

    s16x8_t bfrag = *reinterpret_cast<const s16x8_t*>(
        hbf + (size_t)qnode * 32 + (lane >> 4) * 8);
    const float qd2 = d2b[qnode];
    const float nqd2h = -0.5f * qd2;

    unsigned top[KPW];
#pragma unroll
    for (int j = 0; j < KPW; ++j) top[j] = 0xFFFFFFFFu;
    // V1/V2: runtime accept-all threshold (sign bit set > any positive-float key)
    unsigned thresh = (V == 3) ? 0xFFFFFFFFu
                               : (__float_as_uint(qd2) | 0x80000001u);
    int pcnt = 0;

    const char* gtw = (const char*)til + (size_t)g * 262144
                    + (size_t)par * 1024 + (size_t)lane * 16;
    const float* d2s = reinterpret_cast<const float*>(smem + SD2);
    unsigned* stkl = reinterpret_cast<unsigned*>(smem + STK + wid * 4096) + lane;

    __syncthreads();

    s16x8_t af[4];
#pragma unroll
    for (int i = 0; i < 4; ++i)
        af[i] = *reinterpret_cast<const s16x8_t*>(gtw + i * 2048);

    for (int c = 0; c < 32; ++c) {
        s16x8_t an[4];
        if (c < 31) {
#pragma unroll
            for (int i = 0; i < 4; ++i)
                an[i] = *reinterpret_cast<const s16x8_t*>(
                    gtw + (size_t)(c + 1) * 8192 + i * 2048);
        } else {
#pragma unroll
            for (int i = 0; i < 4; ++i) an[i] = af[i];
        }
        f32x4_t cv[4];
#pragma unroll
        for (int i = 0; i < 4; ++i)
            cv[i] = *reinterpret_cast<const f32x4_t*>(
                d2s + c * 128 + (i * 2 + par) * 16 + rg);
#pragma unroll
        for (int i = 0; i < 4; ++i) {
            const int t = i * 2 + par;
            f32x4_t acc;
#pragma unroll
            for (int r = 0; r < 4; ++r) acc[r] = fmaf(-0.5f, cv[i][r], nqd2h);
            acc = __builtin_amdgcn_mfma_f32_16x16x32_bf16(af[i], bfrag, acc, 0, 0, 0);
            const int cid0 = c * CHK + t * 16 + rg;
#pragma unroll
            for (int r = 0; r < 4; ++r) {
                unsigned key = (__float_as_uint(acc[r]) & 0xFFFFF000u)
                             | (unsigned)(cid0 + r);
                if (V == 0) {
                    asm volatile("" :: "v"(key));   // keep MFMA+key live (DCE guard)
                } else if (V == 1) {
                    pcnt += (key < thresh) ? 1 : 0;
                } else if (V == 2) {
                    stkl[(pcnt & 15) * 64] = key;
                    pcnt += (key < thresh) ? 1 : 0;
                } else {
                    stkl[pcnt * 64] = key;
                    pcnt += (key < thresh) ? 1 : 0;
                }
            }
            if (V >= 1 && __any(pcnt >= TRIG)) {
                if (V == 3) {
#pragma unroll 1
                    for (int j = 0; j < STKD; ++j) {
                        if (!__any(pcnt > j)) break;
                        unsigned kk = stkl[j * 64];
                        unsigned k = (j < pcnt) ? kk : 0xFFFFFFFFu;
                        CHAIN14(k);
                    }
                    thresh = top[KPW - 1];
                }
                pcnt = 0;
            }
        }
#pragma unroll
        for (int i = 0; i < 4; ++i) af[i] = an[i];
    }
    if (V == 3) {
#pragma unroll 1
        for (int j = 0; j < STKD; ++j) {
            if (!__any(pcnt > j)) break;
            unsigned kk = stkl[j * 64];
            unsigned k = (j < pcnt) ? kk : 0xFFFFFFFFu;
            CHAIN14(k);
        }
    }
    unsigned sum = (unsigned)pcnt;
    if (V == 3) {
#pragma unroll
        for (int j = 0; j < KPW; ++j) sum += top[j];
    }
    scratch[(unsigned)(blockIdx.x * 512 + tid) & 32767u] = sum;
}

__global__ void k_ab_arm(unsigned* flag) {
    if (threadIdx.x == 0)
        __hip_atomic_store(flag, AB_MAGIC, __ATOMIC_RELAXED,
                           __HIP_MEMORY_SCOPE_AGENT);
}

// ------------- aggregate: h_out = elu(A + max_k Bv[nbr]); LAST: fused output MLP -------------
template <bool LAST>
__global__ __launch_bounds__(128) void k_aggregate(
    const float* __restrict__ A, const float* __restrict__ Bv,
    const int* __restrict__ idx,
    float* __restrict__ hOut, float* __restrict__ d2Out,
    unsigned short* __restrict__ hbf, unsigned short* __restrict__ til,
    float* __restrict__ d2b,
    const float* __restrict__ w1, const float* __restrict__ b1,
    const float* __restrict__ w2, const float* __restrict__ b2,
    const float* __restrict__ w3, const float* __restrict__ b3,
    float* __restrict__ out)
{
    __shared__ float sw1[1024];
    __shared__ float sb1[32];
    __shared__ float sw2[512];
    __shared__ float sb2[16];
    __shared__ float sw3[128];
    __shared__ float sb3[8];
    int tid = threadIdx.x;
    if (LAST) {
        for (int i = tid; i < 1024; i += 128) sw1[i] = w1[i];
        for (int i = tid; i < 512; i += 128) sw2[i] = w2[i];
        sw3[tid] = w3[tid];                      // 128 threads, 128 entries
        if (tid < 32) sb1[tid] = b1[tid];
        if (tid >= 32 && tid < 48) sb2[tid - 32] = b2[tid - 32];
        if (tid >= 48 && tid < 56) sb3[tid - 48] = b3[tid - 48];
        __syncthreads();
    }

    int node = blockIdx.x * 128 + tid;
    int g = node >> 12;
    const int* ip = idx + (size_t)node * KNN;

    float4 m[8];
#pragma unroll
    for (int j = 0; j < 8; ++j) m[j] = make_float4(-1e30f, -1e30f, -1e30f, -1e30f);

    for (int k = 0; k < KNN; ++k) {
        int cand = (g << 12) + ip[k];
        const float4* bp = reinterpret_cast<const float4*>(Bv) + (size_t)cand * 8;
#pragma unroll
        for (int j = 0; j < 8; ++j) {
            float4 b = bp[j];
            m[j].x = fmaxf(m[j].x, b.x);
            m[j].y = fmaxf(m[j].y, b.y);
            m[j].z = fmaxf(m[j].z, b.z);
            m[j].w = fmaxf(m[j].w, b.w);
        }
    }
    const float4* ap = reinterpret_cast<const float4*>(A) + (size_t)node * 8;
    float hv[32];
    float d2 = 0.f;
#pragma unroll
    for (int j = 0; j < 8; ++j) {
        float4 a = ap[j];
        float4 v;
        v.x = elu_f(a.x + m[j].x);
        v.y = elu_f(a.y + m[j].y);
        v.z = elu_f(a.z + m[j].z);
        v.w = elu_f(a.w + m[j].w);
        d2 = fmaf(v.x, v.x, d2);
        d2 = fmaf(v.y, v.y, d2);
        d2 = fmaf(v.z, v.z, d2);
        d2 = fmaf(v.w, v.w, d2);
        hv[4 * j] = v.x; hv[4 * j + 1] = v.y; hv[4 * j + 2] = v.z; hv[4 * j + 3] = v.w;
    }

    if (!LAST) {
        float4* hp = reinterpret_cast<float4*>(hOut) + (size_t)node * 8;
#pragma unroll
        for (int j = 0; j < 8; ++j)
            hp[j] = make_float4(hv[4 * j], hv[4 * j + 1], hv[4 * j + 2], hv[4 * j + 3]);
        d2Out[node] = d2;
        pack_node(node, hv, hbf, til, d2b);
    } else {
        float o1[32];
#pragma unroll
        for (int o = 0; o < 32; ++o) {
            float s = sb1[o];
#pragma unroll
            for (int f = 0; f < 32; ++f) s = fmaf(hv[f], sw1[f * 32 + o], s);
            o1[o] = elu_f(s);
        }
        float o2[16];
#pragma unroll
        for (int o = 0; o < 16; ++o) {
            float s = sb2[o];
#pragma unroll
            for (int f = 0; f < 32; ++f) s = fmaf(o1[f], sw2[f * 16 + o], s);
            o2[o] = elu_f(s);
        }
        float o3[8];
#pragma unroll
        for (int o = 0; o < 8; ++o) {
            float s = sb3[o];
#pragma unroll
            for (int f = 0; f < 16; ++f) s = fmaf(o2[f], sw3[f * 8 + o], s);
            o3[o] = s;
        }
        float4* op = reinterpret_cast<float4*>(out) + (size_t)node * 2;
        op[0] = make_float4(o3[0], o3[1], o3[2], o3[3]);
        op[1] = make_float4(o3[4], o3[5], o3[6], o3[7]);
        out[(size_t)BN * 8 + node] = (float)(node >> 12);
    }
}

extern "C" void kernel_launch(void* const* d_in, const int* in_sizes, int n_in,
                              void* d_out, int out_size, void* d_ws, size_t ws_size,
                              hipStream_t stream)
{
    (void)in_sizes; (void)n_in; (void)out_size;
    const float* x      = (const float*)d_in[0];
    const float* enc_w1 = (const float*)d_in[2];
    const float* enc_b1 = (const float*)d_in[3];
    const float* enc_w2 = (const float*)d_in[4];
    const float* enc_b2 = (const float*)d_in[5];
    const float* conv_w[3] = { (const float*)d_in[6], (const float*)d_in[8], (const float*)d_in[10] };
    const float* conv_b[3] = { (const float*)d_in[7], (const float*)d_in[9], (const float*)d_in[11] };
    const float* out_w1 = (const float*)d_in[12];
    const float* out_b1 = (const float*)d_in[13];
    const float* out_w2 = (const float*)d_in[14];
    const float* out_b2 = (const float*)d_in[15];
    const float* out_w3 = (const float*)d_in[16];
    const float* out_b3 = (const float*)d_in[17];

    char* ws = (char*)d_ws;
    float*          hA   = (float*)(ws + 0);                  // 4 MB
    float*          hB   = (float*)(ws + 4194304);            // 4 MB
    unsigned short* hbfA = (unsigned short*)(ws + 8388608);   // 2 MB
    unsigned short* hbfB = (unsigned short*)(ws + 10485760);  // 2 MB
    unsigned short* tilA = (unsigned short*)(ws + 12582912);  // 2 MB
    unsigned short* tilB = (unsigned short*)(ws + 14680064);  // 2 MB
    float*          d2A  = (float*)(ws + 16777216);           // 128 KB
    float*          d2B  = (float*)(ws + 16908288);           // 128 KB
    float*          d2bA = (float*)(ws + 17039360);           // 128 KB
    float*          d2bB = (float*)(ws + 17170432);           // 128 KB
    int*            idx  = (int*)(ws + 17301504);             // 3.15 MB
    float*          Abuf = (float*)(ws + 20447232);           // 4 MB
    float*          Bbuf = (float*)(ws + 24641536);           // 4 MB

    k_encoder<<<256, 128, 0, stream>>>(x, enc_w1, enc_b1, enc_w2, enc_b2,
                                       hA, d2A, hbfA, tilA, d2bA);

    // one-shot scan ablation (early-exits after first iteration via flag)
    if (ws_size >= (size_t)AB_END) {
        unsigned* abflag = (unsigned*)(ws + AB_FLAG_OFF);
        unsigned* abscr  = (unsigned*)(ws + AB_SCR_OFF);
        k_ablate<0><<<1024, 512, 0, stream>>>(tilA, hbfA, d2bA, abscr, abflag);
        k_ablate<1><<<1024, 512, 0, stream>>>(tilA, hbfA, d2bA, abscr, abflag);
        k_ablate<2><<<1024, 512, 0, stream>>>(tilA, hbfA, d2bA, abscr, abflag);
        k_ablate<3><<<1024, 512, 0, stream>>>(tilA, hbfA, d2bA, abscr, abflag);
        k_ab_arm<<<1, 64, 0, stream>>>(abflag);
    }

    float* hin = hA;   float* d2in = d2A;   float* d2bin = d2bA;
    unsigned short* hbfin = hbfA; unsigned short* tilin = tilA;
    float* hout = hB;  float* d2out = d2B;  float* d2bout = d2bB;
    unsigned short* hbfout = hbfB; unsigned short* tilout = tilB;

    for (int l = 0; l < 3; ++l) {
        k_knn<<<512, 512, 0, stream>>>(tilin, hbfin, d2bin, hin, d2in, idx,
                                       conv_w[l], conv_b[l], Abuf, Bbuf);
        if (l < 2) {
            k_aggregate<false><<<256, 128, 0, stream>>>(
                Abuf, Bbuf, idx, hout, d2out, hbfout, tilout, d2bout,
                nullptr, nullptr, nullptr, nullptr, nullptr, nullptr, nullptr);
        } else {
            k_aggregate<true><<<256, 128, 0, stream>>>(
                Abuf, Bbuf, idx, nullptr, nullptr, nullptr, nullptr, nullptr,
                out_w1, out_b1, out_w2, out_b2, out_w3, out_b3, (float*)d_out);
        }
        float* tf; unsigned short* ts;
        tf = hin; hin = hout; hout = tf;
        tf = d2in; d2in = d2out; d2out = tf;
        tf = d2bin; d2bin = d2bout; d2bout = tf;
        ts = hbfin; hbfin = hbfout; hbfout = ts;
        ts = tilin; tilin = tilout; tilout = ts;
    }
}

// Round 9
// 587.241 us; speedup vs baseline: 1.0211x; 1.0211x over previous
//
#include <hip/hip_runtime.h>
#include <cstddef>
#include <cstdint>

#define BN    32768   // B*N
#define NG    4096    // nodes per graph
#define KNN   24
#define KPW   14      // per-lane partial top over its 1/8 candidate subset
#define KM    32      // merged candidate pool for exact refine
#define CHK   128     // candidates per chunk
#define NBQ   64      // queries per knn block
#define STKD  16      // pending-stack depth per lane
#define TRIG  13      // flush trigger: pcnt<=12 pre-tile, +4 writes at slots<=15

typedef float f32x4_t __attribute__((ext_vector_type(4)));
typedef short s16x8_t __attribute__((ext_vector_type(8)));

__device__ __forceinline__ float elu_f(float x) {
    return x > 0.f ? x : expm1f(x);
}

__device__ __forceinline__ unsigned short f2bf(float f) {
    unsigned u = __float_as_uint(f);
    unsigned r = (u + 0x7FFFu + ((u >> 16) & 1u)) >> 16;   // RNE
    return (unsigned short)r;
}

__device__ __forceinline__ void gload_lds16(const void* g, void* l) {
    __builtin_amdgcn_global_load_lds(
        (const __attribute__((address_space(1))) unsigned*)g,
        (__attribute__((address_space(3))) unsigned*)l, 16, 0, 0);
}

// pack one node's 32 features: bf16 linear, bf16 MFMA-A-tiled, bf16-consistent d2
__device__ __forceinline__ void pack_node(int n, const float* hv,
    unsigned short* __restrict__ hbf, unsigned short* __restrict__ til,
    float* __restrict__ d2b)
{
    __align__(16) unsigned short us[32];
    float s = 0.f;
#pragma unroll
    for (int k = 0; k < 32; ++k) {
        us[k] = f2bf(hv[k]);
        float v = __uint_as_float(((unsigned)us[k]) << 16);
        s = fmaf(v, v, s);
    }
    d2b[n] = s;
    const uint4* up = reinterpret_cast<const uint4*>(us);
    uint4* lp = reinterpret_cast<uint4*>(hbf + (size_t)n * 32);
#pragma unroll
    for (int j = 0; j < 4; ++j) lp[j] = up[j];
    const int g = n >> 12, ln = n & 4095, tile = ln >> 4, c = ln & 15;
    unsigned short* tb = til + (size_t)g * 131072 + tile * 512 + c * 8;
#pragma unroll
    for (int kg = 0; kg < 4; ++kg)
        *reinterpret_cast<uint4*>(tb + kg * 128) = up[kg];
}

// ---------------- encoder: x[BN,4] -> h[BN,32] (+bf16 pack, d2, d2b) ----------------
// 256 blocks x 128 threads: one block per CU (all 256 CUs active)
__global__ __launch_bounds__(128) void k_encoder(
    const float* __restrict__ x,
    const float* __restrict__ w1, const float* __restrict__ b1,
    const float* __restrict__ w2, const float* __restrict__ b2,
    float* __restrict__ hOut, float* __restrict__ d2Out,
    unsigned short* __restrict__ hbf, unsigned short* __restrict__ til,
    float* __restrict__ d2b)
{
    __shared__ float sw1[4 * 32];
    __shared__ float sb1[32];
    __shared__ float sw2[32 * 32];
    __shared__ float sb2[32];
    int tid = threadIdx.x;
    sw1[tid] = w1[tid];                     // 128 threads, 128 entries
    if (tid < 32) sb1[tid] = b1[tid];
    for (int i = tid; i < 1024; i += 128) sw2[i] = w2[i];
    if (tid >= 32 && tid < 64) sb2[tid - 32] = b2[tid - 32];
    __syncthreads();

    int node = blockIdx.x * 128 + tid;
    float4 xv = reinterpret_cast<const float4*>(x)[node];

    float h1[32];
#pragma unroll
    for (int o = 0; o < 32; ++o) {
        float s = sb1[o];
        s = fmaf(xv.x, sw1[o], s);
        s = fmaf(xv.y, sw1[32 + o], s);
        s = fmaf(xv.z, sw1[64 + o], s);
        s = fmaf(xv.w, sw1[96 + o], s);
        h1[o] = elu_f(s);
    }
    float h2[32];
    float d2 = 0.f;
#pragma unroll
    for (int o = 0; o < 32; ++o) {
        float s = sb2[o];
#pragma unroll
        for (int f = 0; f < 32; ++f) s = fmaf(h1[f], sw2[f * 32 + o], s);
        float v = elu_f(s);
        h2[o] = v;
        d2 = fmaf(v, v, d2);
    }
    float4* hp = reinterpret_cast<float4*>(hOut) + (size_t)node * 8;
#pragma unroll
    for (int j = 0; j < 8; ++j)
        hp[j] = make_float4(h2[4 * j], h2[4 * j + 1], h2[4 * j + 2], h2[4 * j + 3]);
    d2Out[node] = d2;
    pack_node(node, h2, hbf, til, d2b);
}

// sorted-ascending chain insert into top[KPW]
#define CHAIN14(nk_) do { \
    unsigned nk = (nk_); \
    _Pragma("unroll") \
    for (int jj = 0; jj < KPW; ++jj) { \
        unsigned tj = top[jj]; \
        unsigned lo = nk < tj ? nk : tj; \
        unsigned hi = nk < tj ? tj : nk; \
        top[jj] = lo; nk = hi; \
    } \
} while (0)

// ------------- MFMA kNN scan + P1 pool merge (epilogue split to k_refine) -------------
// 512 blocks x 512 threads; block = 64 queries, 8 waves = 4 query tiles x 2
// cand-tile parities. Scan is barrier-free; A-fragments stream global(L2)->
// register; whole-graph d2 (16KB) staged to LDS once. Selection keys are raw
// MFMA acc bits; accept path branchless/exec-free; per-lane sorted top-14 via
// 16-deep stacks. After the list dump, waves 1-7 EXIT; wave 0 merges each
// query's 8 lists -> KM pool ids written to global (u16, aliased into the
// next layer's til buffer — dead until k_aggregate writes it).
// Rationale (R8 ablation): pure scan runs at 82% VALUBusy; the old in-kernel
// epilogue ran at ~15% efficiency and cost ~40-80us wall of the 165us.
__global__ __launch_bounds__(512, 4) void k_scan(
    const unsigned short* __restrict__ til,
    const unsigned short* __restrict__ hbf,
    const float* __restrict__ d2b,
    unsigned short* __restrict__ mgs)
{
    __shared__ __align__(16) unsigned char smem[49152];
    constexpr int SD2 = 0;        // 16KB whole-graph bf16-consistent d2
    constexpr int STK = 16384;    // 8 waves x 4096B pending stacks (16 deep)
    constexpr int LST = 16384;    // sorted lists (reuse stacks after drain)

    const int tid = threadIdx.x;
    const int lane = tid & 63;
    const int wid = __builtin_amdgcn_readfirstlane(tid >> 6);
    const int qt = wid >> 1;
    const int par = wid & 1;
    const int bid = blockIdx.x;
    const int g = bid >> 6;
    const int gbase = g << 12;
    const int blockq = (bid & 63) * NBQ;
    const int qnode = gbase + blockq + qt * 16 + (lane & 15);
    const int rg = (lane >> 4) * 4;   // candidate row group base within tile

    // stage whole-graph d2 (4096 floats) once: 2 passes x 8 waves x 1KB
    gload_lds16(d2b + gbase + wid * 256 + lane * 4, smem + SD2 + wid * 1024);
    gload_lds16(d2b + gbase + 2048 + wid * 256 + lane * 4,
                smem + SD2 + 8192 + wid * 1024);

    // B fragment: query (lane&15) of this wave's tile, k-slice (lane>>4)*8..+8
    s16x8_t bfrag = *reinterpret_cast<const s16x8_t*>(
        hbf + (size_t)qnode * 32 + (lane >> 4) * 8);
    const float qd2 = d2b[qnode];
    const float nqd2h = -0.5f * qd2;

    unsigned top[KPW];
#pragma unroll
    for (int j = 0; j < KPW; ++j) top[j] = 0xFFFFFFFFu;
    unsigned thresh = 0xFFFFFFFFu;
    int pcnt = 0;

    // this wave's A-fragment stream base: tiles {par, par+2, par+4, par+6}
    const char* gtw = (const char*)til + (size_t)g * 262144
                    + (size_t)par * 1024 + (size_t)lane * 16;
    const float* d2s = reinterpret_cast<const float*>(smem + SD2);
    // per-lane element pointer into this wave's stack: slot j at stkl[j*64]
    unsigned* stkl = reinterpret_cast<unsigned*>(smem + STK + wid * 4096) + lane;

    __syncthreads();   // d2 staged

    // prologue: prefetch chunk 0 A-fragments into registers
    s16x8_t af[4];
#pragma unroll
    for (int i = 0; i < 4; ++i)
        af[i] = *reinterpret_cast<const s16x8_t*>(gtw + i * 2048);

    for (int c = 0; c < 32; ++c) {
        s16x8_t an[4];
        if (c < 31) {
#pragma unroll
            for (int i = 0; i < 4; ++i)
                an[i] = *reinterpret_cast<const s16x8_t*>(
                    gtw + (size_t)(c + 1) * 8192 + i * 2048);
        } else {
#pragma unroll
            for (int i = 0; i < 4; ++i) an[i] = af[i];
        }
        // candidate d2 for this chunk's 4 tiles (LDS, broadcast within 16 lanes)
        f32x4_t cv[4];
#pragma unroll
        for (int i = 0; i < 4; ++i)
            cv[i] = *reinterpret_cast<const f32x4_t*>(
                d2s + c * 128 + (i * 2 + par) * 16 + rg);
#pragma unroll
        for (int i = 0; i < 4; ++i) {
            const int t = i * 2 + par;
            f32x4_t acc;
#pragma unroll
            for (int r = 0; r < 4; ++r) acc[r] = fmaf(-0.5f, cv[i][r], nqd2h);
            acc = __builtin_amdgcn_mfma_f32_16x16x32_bf16(af[i], bfrag, acc, 0, 0, 0);
            const int cid0 = c * CHK + t * 16 + rg;
#pragma unroll
            for (int r = 0; r < 4; ++r) {
                // acc = -(d/2) <= 0; unsigned-ascending bit pattern == ascending d.
                unsigned key = (__float_as_uint(acc[r]) & 0xFFFFF000u)
                             | (unsigned)(cid0 + r);
                // branchless, exec-free accept
                stkl[pcnt * 64] = key;
                pcnt += (key < thresh) ? 1 : 0;
            }
            if (__any(pcnt >= TRIG)) {
#pragma unroll 1
                for (int j = 0; j < STKD; ++j) {
                    if (!__any(pcnt > j)) break;
                    unsigned kk = stkl[j * 64];                   // uncond read
                    unsigned k = (j < pcnt) ? kk : 0xFFFFFFFFu;   // select
                    CHAIN14(k);
                }
                pcnt = 0;
                thresh = top[KPW - 1];
            }
        }
#pragma unroll
        for (int i = 0; i < 4; ++i) af[i] = an[i];
    }
    // final drain
#pragma unroll 1
    for (int j = 0; j < STKD; ++j) {
        if (!__any(pcnt > j)) break;
        unsigned kk = stkl[j * 64];
        unsigned k = (j < pcnt) ? kk : 0xFFFFFFFFu;
        CHAIN14(k);
    }
    __syncthreads();   // all drains done before list region overwrites stacks

    // dump sorted lists
    unsigned* lst = reinterpret_cast<unsigned*>(smem + LST);
#pragma unroll
    for (int j = 0; j < KPW; ++j) lst[(wid * 64 + lane) * KPW + j] = top[j];
    __syncthreads();

    if (wid != 0) return;   // waves 1-7 done; wave 0 merges

    // P1: per query, merge its 8 sorted lists -> KM pool ids -> global u16
    {
        const int q = tid;   // 0..63
        unsigned mt[KM];
#pragma unroll
        for (int j = 0; j < KM; ++j) mt[j] = 0xFFFFFFFFu;
        for (int li = 0; li < 8; ++li) {
            const unsigned* lk = lst +
                (((q >> 4) * 2 + (li >> 2)) * 64 + (li & 3) * 16 + (q & 15)) * KPW;
            for (int j = 0; j < KPW; ++j) {
                unsigned key = lk[j];
                if (key >= mt[KM - 1]) break;
                unsigned nk = key;
#pragma unroll
                for (int jj = 0; jj < KM; ++jj) {
                    unsigned tj = mt[jj];
                    unsigned lo = nk < tj ? nk : tj;
                    unsigned hi = nk < tj ? tj : nk;
                    mt[jj] = lo; nk = hi;
                }
            }
        }
        unsigned short* mrow = mgs + (size_t)(gbase + blockq + q) * 32;
#pragma unroll
        for (int s = 0; s < KM; ++s)
            mrow[s] = (unsigned short)(mt[s] & 0xFFFu);
    }
}

// ------------- refine: exact top-24 from the KM pool + A/Bv precompute -------------
// 2048 blocks x 128 threads, 16 queries/block, ~12.6KB LDS -> 8 blocks/CU
// co-resident: the serial-ish phases of different blocks overlap. P3 is a
// fully-parallel rank-select (no serial insert chain): rank_i = #{j: (d_j,j)
// < (d_i,i)} over the 32-pool; ranks are unique, the 24 smallest win.
__global__ __launch_bounds__(128) void k_refine(
    const unsigned short* __restrict__ mgs,
    const float* __restrict__ hf,
    const float* __restrict__ d2x,
    const float* __restrict__ cw, const float* __restrict__ cb,
    int* __restrict__ idxOut,
    float* __restrict__ Abuf, float* __restrict__ Bbuf)
{
    __shared__ float sw[2048];
    __shared__ float sb[32];
    __shared__ __align__(16) float dstv[16][36];   // pad 36: bank-spread + 16B rows
    __shared__ int mgl[16][32];

    const int tid = threadIdx.x;
    const int bid = blockIdx.x;
    const int g = bid >> 8;
    const int gbase = g << 12;
    const int blockq = (bid & 255) * 16;

    for (int i = tid; i < 2048; i += 128) sw[i] = cw[i];
    if (tid < 32) sb[tid] = cb[tid];
    for (int i = tid; i < 512; i += 128)
        mgl[i >> 5][i & 31] =
            (int)mgs[(size_t)(gbase + blockq + (i >> 5)) * 32 + (i & 31)];
    __syncthreads();

    const int q  = tid >> 3;        // 0..15
    const int s0 = tid & 7;
    const int qn = gbase + blockq + q;

    // P2: exact fp32 distances (8 threads/query, 4 cands each)
    const float4* qp = reinterpret_cast<const float4*>(hf) + (size_t)qn * 8;
    float4 qf[8];
#pragma unroll
    for (int j = 0; j < 8; ++j) qf[j] = qp[j];
    const float qd2e = d2x[qn];
    int cids[4];
#pragma unroll
    for (int ss = 0; ss < 4; ++ss) {
        const int s = s0 + ss * 8;
        const int cid = mgl[q][s];
        cids[ss] = cid;
        const int cn = gbase + cid;
        const float4* cp = reinterpret_cast<const float4*>(hf) + (size_t)cn * 8;
        float ax = 0.f, ay = 0.f, az = 0.f, aw = 0.f;
#pragma unroll
        for (int jj = 0; jj < 8; ++jj) {
            float4 cc = cp[jj];
            ax = fmaf(qf[jj].x, cc.x, ax);
            ay = fmaf(qf[jj].y, cc.y, ay);
            az = fmaf(qf[jj].z, cc.z, az);
            aw = fmaf(qf[jj].w, cc.w, aw);
        }
        float dot = (ax + ay) + (az + aw);
        dstv[q][s] = fmaf(-2.f, dot, qd2e + d2x[cn]);
    }
    __syncthreads();

    // P3: parallel rank-select of the exact top-24 (deterministic via slot tiebreak)
    {
        float dsr[32];
        const float4* dvp = reinterpret_cast<const float4*>(dstv[q]);
#pragma unroll
        for (int jj = 0; jj < 8; ++jj) {
            float4 t = dvp[jj];
            dsr[4 * jj] = t.x; dsr[4 * jj + 1] = t.y;
            dsr[4 * jj + 2] = t.z; dsr[4 * jj + 3] = t.w;
        }
        int* o = idxOut + (size_t)qn * KNN;
#pragma unroll
        for (int ss = 0; ss < 4; ++ss) {
            const int s = s0 + ss * 8;
            const float di = dsr[s];
            int rank = 0;
#pragma unroll
            for (int j = 0; j < 32; ++j)
                rank += (dsr[j] < di || (dsr[j] == di && j < s)) ? 1 : 0;
            if (rank < KNN) o[rank] = cids[ss];
        }
    }

    // A/B precompute: A = h@(W1-W2)+b, Bv = h@W2 (h rows direct from global/L1)
    {
        const int o0 = s0 * 4;
        float hreg[32];
#pragma unroll
        for (int j = 0; j < 8; ++j) {
            float4 v = qp[j];   // node row == query row (same node)
            hreg[4 * j] = v.x; hreg[4 * j + 1] = v.y;
            hreg[4 * j + 2] = v.z; hreg[4 * j + 3] = v.w;
        }
        float4 s1 = make_float4(0.f, 0.f, 0.f, 0.f);
        float4 s2 = make_float4(0.f, 0.f, 0.f, 0.f);
#pragma unroll
        for (int f = 0; f < 32; ++f) {
            float hv = hreg[f];
            float4 wa = *reinterpret_cast<const float4*>(sw + f * 32 + o0);
            float4 wb = *reinterpret_cast<const float4*>(sw + (32 + f) * 32 + o0);
            s1.x = fmaf(hv, wa.x, s1.x); s1.y = fmaf(hv, wa.y, s1.y);
            s1.z = fmaf(hv, wa.z, s1.z); s1.w = fmaf(hv, wa.w, s1.w);
            s2.x = fmaf(hv, wb.x, s2.x); s2.y = fmaf(hv, wb.y, s2.y);
            s2.z = fmaf(hv, wb.z, s2.z); s2.w = fmaf(hv, wb.w, s2.w);
        }
        float4 bv = *reinterpret_cast<const float4*>(sb + o0);
        float4 av = make_float4(s1.x - s2.x + bv.x, s1.y - s2.y + bv.y,
                                s1.z - s2.z + bv.z, s1.w - s2.w + bv.w);
        *reinterpret_cast<float4*>(Abuf + (size_t)qn * 32 + o0) = av;
        *reinterpret_cast<float4*>(Bbuf + (size_t)qn * 32 + o0) = s2;
    }
}

// ------------- aggregate: h_out = elu(A + max_k Bv[nbr]); LAST: fused output MLP -------------
template <bool LAST>
__global__ __launch_bounds__(128) void k_aggregate(
    const float* __restrict__ A, const float* __restrict__ Bv,
    const int* __restrict__ idx,
    float* __restrict__ hOut, float* __restrict__ d2Out,
    unsigned short* __restrict__ hbf, unsigned short* __restrict__ til,
    float* __restrict__ d2b,
    const float* __restrict__ w1, const float* __restrict__ b1,
    const float* __restrict__ w2, const float* __restrict__ b2,
    const float* __restrict__ w3, const float* __restrict__ b3,
    float* __restrict__ out)
{
    __shared__ float sw1[1024];
    __shared__ float sb1[32];
    __shared__ float sw2[512];
    __shared__ float sb2[16];
    __shared__ float sw3[128];
    __shared__ float sb3[8];
    int tid = threadIdx.x;
    if (LAST) {
        for (int i = tid; i < 1024; i += 128) sw1[i] = w1[i];
        for (int i = tid; i < 512; i += 128) sw2[i] = w2[i];
        sw3[tid] = w3[tid];                      // 128 threads, 128 entries
        if (tid < 32) sb1[tid] = b1[tid];
        if (tid >= 32 && tid < 48) sb2[tid - 32] = b2[tid - 32];
        if (tid >= 48 && tid < 56) sb3[tid - 48] = b3[tid - 48];
        __syncthreads();
    }

    int node = blockIdx.x * 128 + tid;
    int g = node >> 12;
    const int* ip = idx + (size_t)node * KNN;

    float4 m[8];
#pragma unroll
    for (int j = 0; j < 8; ++j) m[j] = make_float4(-1e30f, -1e30f, -1e30f, -1e30f);

    for (int k = 0; k < KNN; ++k) {
        int cand = (g << 12) + ip[k];
        const float4* bp = reinterpret_cast<const float4*>(Bv) + (size_t)cand * 8;
#pragma unroll
        for (int j = 0; j < 8; ++j) {
            float4 b = bp[j];
            m[j].x = fmaxf(m[j].x, b.x);
            m[j].y = fmaxf(m[j].y, b.y);
            m[j].z = fmaxf(m[j].z, b.z);
            m[j].w = fmaxf(m[j].w, b.w);
        }
    }
    const float4* ap = reinterpret_cast<const float4*>(A) + (size_t)node * 8;
    float hv[32];
    float d2 = 0.f;
#pragma unroll
    for (int j = 0; j < 8; ++j) {
        float4 a = ap[j];
        float4 v;
        v.x = elu_f(a.x + m[j].x);
        v.y = elu_f(a.y + m[j].y);
        v.z = elu_f(a.z + m[j].z);
        v.w = elu_f(a.w + m[j].w);
        d2 = fmaf(v.x, v.x, d2);
        d2 = fmaf(v.y, v.y, d2);
        d2 = fmaf(v.z, v.z, d2);
        d2 = fmaf(v.w, v.w, d2);
        hv[4 * j] = v.x; hv[4 * j + 1] = v.y; hv[4 * j + 2] = v.z; hv[4 * j + 3] = v.w;
    }

    if (!LAST) {
        float4* hp = reinterpret_cast<float4*>(hOut) + (size_t)node * 8;
#pragma unroll
        for (int j = 0; j < 8; ++j)
            hp[j] = make_float4(hv[4 * j], hv[4 * j + 1], hv[4 * j + 2], hv[4 * j + 3]);
        d2Out[node] = d2;
        pack_node(node, hv, hbf, til, d2b);
    } else {
        float o1[32];
#pragma unroll
        for (int o = 0; o < 32; ++o) {
            float s = sb1[o];
#pragma unroll
            for (int f = 0; f < 32; ++f) s = fmaf(hv[f], sw1[f * 32 + o], s);
            o1[o] = elu_f(s);
        }
        float o2[16];
#pragma unroll
        for (int o = 0; o < 16; ++o) {
            float s = sb2[o];
#pragma unroll
            for (int f = 0; f < 32; ++f) s = fmaf(o1[f], sw2[f * 16 + o], s);
            o2[o] = elu_f(s);
        }
        float o3[8];
#pragma unroll
        for (int o = 0; o < 8; ++o) {
            float s = sb3[o];
#pragma unroll
            for (int f = 0; f < 16; ++f) s = fmaf(o2[f], sw3[f * 8 + o], s);
            o3[o] = s;
        }
        float4* op = reinterpret_cast<float4*>(out) + (size_t)node * 2;
        op[0] = make_float4(o3[0], o3[1], o3[2], o3[3]);
        op[1] = make_float4(o3[4], o3[5], o3[6], o3[7]);
        out[(size_t)BN * 8 + node] = (float)(node >> 12);
    }
}

extern "C" void kernel_launch(void* const* d_in, const int* in_sizes, int n_in,
                              void* d_out, int out_size, void* d_ws, size_t ws_size,
                              hipStream_t stream)
{
    (void)in_sizes; (void)n_in; (void)out_size; (void)ws_size;
    const float* x      = (const float*)d_in[0];
    const float* enc_w1 = (const float*)d_in[2];
    const float* enc_b1 = (const float*)d_in[3];
    const float* enc_w2 = (const float*)d_in[4];
    const float* enc_b2 = (const float*)d_in[5];
    const float* conv_w[3] = { (const float*)d_in[6], (const float*)d_in[8], (const float*)d_in[10] };
    const float* conv_b[3] = { (const float*)d_in[7], (const float*)d_in[9], (const float*)d_in[11] };
    const float* out_w1 = (const float*)d_in[12];
    const float* out_b1 = (const float*)d_in[13];
    const float* out_w2 = (const float*)d_in[14];
    const float* out_b2 = (const float*)d_in[15];
    const float* out_w3 = (const float*)d_in[16];
    const float* out_b3 = (const float*)d_in[17];

    char* ws = (char*)d_ws;
    float*          hA   = (float*)(ws + 0);                  // 4 MB
    float*          hB   = (float*)(ws + 4194304);            // 4 MB
    unsigned short* hbfA = (unsigned short*)(ws + 8388608);   // 2 MB
    unsigned short* hbfB = (unsigned short*)(ws + 10485760);  // 2 MB
    unsigned short* tilA = (unsigned short*)(ws + 12582912);  // 2 MB
    unsigned short* tilB = (unsigned short*)(ws + 14680064);  // 2 MB
    float*          d2A  = (float*)(ws + 16777216);           // 128 KB
    float*          d2B  = (float*)(ws + 16908288);           // 128 KB
    float*          d2bA = (float*)(ws + 17039360);           // 128 KB
    float*          d2bB = (float*)(ws + 17170432);           // 128 KB
    int*            idx  = (int*)(ws + 17301504);             // 3.15 MB
    float*          Abuf = (float*)(ws + 20447232);           // 4 MB
    float*          Bbuf = (float*)(ws + 24641536);           // 4 MB

    k_encoder<<<256, 128, 0, stream>>>(x, enc_w1, enc_b1, enc_w2, enc_b2,
                                       hA, d2A, hbfA, tilA, d2bA);

    float* hin = hA;   float* d2in = d2A;   float* d2bin = d2bA;
    unsigned short* hbfin = hbfA; unsigned short* tilin = tilA;
    float* hout = hB;  float* d2out = d2B;  float* d2bout = d2bB;
    unsigned short* hbfout = hbfB; unsigned short* tilout = tilB;

    for (int l = 0; l < 3; ++l) {
        // pool ids (u16) alias the NEXT til buffer: dead until k_aggregate
        // writes it (stream-ordered after k_refine consumed the pool).
        unsigned short* mgs = tilout;
        k_scan<<<512, 512, 0, stream>>>(tilin, hbfin, d2bin, mgs);
        k_refine<<<2048, 128, 0, stream>>>(mgs, hin, d2in,
                                           conv_w[l], conv_b[l], idx, Abuf, Bbuf);
        if (l < 2) {
            k_aggregate<false><<<256, 128, 0, stream>>>(
                Abuf, Bbuf, idx, hout, d2out, hbfout, tilout, d2bout,
                nullptr, nullptr, nullptr, nullptr, nullptr, nullptr, nullptr);
        } else {
            k_aggregate<true><<<256, 128, 0, stream>>>(
                Abuf, Bbuf, idx, nullptr, nullptr, nullptr, nullptr, nullptr,
                out_w1, out_b1, out_w2, out_b2, out_w3, out_b3, (float*)d_out);
        }
        float* tf; unsigned short* ts;
        tf = hin; hin = hout; hout = tf;
        tf = d2in; d2in = d2out; d2out = tf;
        tf = d2bin; d2bin = d2bout; d2bout = tf;
        ts = hbfin; hbfin = hbfout; hbfout = ts;
        ts = tilin; tilin = tilout; tilout = ts;
    }
}

// Round 10
// 554.069 us; speedup vs baseline: 1.0822x; 1.0599x over previous
//
#include <hip/hip_runtime.h>
#include <cstddef>
#include <cstdint>

#define BN    32768   // B*N
#define NG    4096    // nodes per graph
#define KNN   24
#define KPW   14      // per-lane partial top over its 1/8 candidate subset
#define KM    32      // merged candidate pool for exact refine
#define CHK   128     // candidates per chunk
#define NBQ   64      // queries per knn block
#define STKD  16      // pending-stack depth per lane
#define TRIG  13      // flush trigger: pcnt<=12 pre-tile, +4 writes at slots<=15

typedef float f32x4_t __attribute__((ext_vector_type(4)));
typedef short s16x8_t __attribute__((ext_vector_type(8)));

__device__ __forceinline__ float elu_f(float x) {
    return x > 0.f ? x : expm1f(x);
}

__device__ __forceinline__ unsigned short f2bf(float f) {
    unsigned u = __float_as_uint(f);
    unsigned r = (u + 0x7FFFu + ((u >> 16) & 1u)) >> 16;   // RNE
    return (unsigned short)r;
}

__device__ __forceinline__ void gload_lds16(const void* g, void* l) {
    __builtin_amdgcn_global_load_lds(
        (const __attribute__((address_space(1))) unsigned*)g,
        (__attribute__((address_space(3))) unsigned*)l, 16, 0, 0);
}

// pack one node's 32 features: bf16 linear, bf16 MFMA-A-tiled, bf16-consistent d2
__device__ __forceinline__ void pack_node(int n, const float* hv,
    unsigned short* __restrict__ hbf, unsigned short* __restrict__ til,
    float* __restrict__ d2b)
{
    __align__(16) unsigned short us[32];
    float s = 0.f;
#pragma unroll
    for (int k = 0; k < 32; ++k) {
        us[k] = f2bf(hv[k]);
        float v = __uint_as_float(((unsigned)us[k]) << 16);
        s = fmaf(v, v, s);
    }
    d2b[n] = s;
    const uint4* up = reinterpret_cast<const uint4*>(us);
    uint4* lp = reinterpret_cast<uint4*>(hbf + (size_t)n * 32);
#pragma unroll
    for (int j = 0; j < 4; ++j) lp[j] = up[j];
    const int g = n >> 12, ln = n & 4095, tile = ln >> 4, c = ln & 15;
    unsigned short* tb = til + (size_t)g * 131072 + tile * 512 + c * 8;
#pragma unroll
    for (int kg = 0; kg < 4; ++kg)
        *reinterpret_cast<uint4*>(tb + kg * 128) = up[kg];
}

// ---------------- encoder: x[BN,4] -> h[BN,32] (+bf16 pack, d2, d2b) ----------------
// 256 blocks x 128 threads: one block per CU (all 256 CUs active)
__global__ __launch_bounds__(128) void k_encoder(
    const float* __restrict__ x,
    const float* __restrict__ w1, const float* __restrict__ b1,
    const float* __restrict__ w2, const float* __restrict__ b2,
    float* __restrict__ hOut, float* __restrict__ d2Out,
    unsigned short* __restrict__ hbf, unsigned short* __restrict__ til,
    float* __restrict__ d2b)
{
    __shared__ float sw1[4 * 32];
    __shared__ float sb1[32];
    __shared__ float sw2[32 * 32];
    __shared__ float sb2[32];
    int tid = threadIdx.x;
    sw1[tid] = w1[tid];                     // 128 threads, 128 entries
    if (tid < 32) sb1[tid] = b1[tid];
    for (int i = tid; i < 1024; i += 128) sw2[i] = w2[i];
    if (tid >= 32 && tid < 64) sb2[tid - 32] = b2[tid - 32];
    __syncthreads();

    int node = blockIdx.x * 128 + tid;
    float4 xv = reinterpret_cast<const float4*>(x)[node];

    float h1[32];
#pragma unroll
    for (int o = 0; o < 32; ++o) {
        float s = sb1[o];
        s = fmaf(xv.x, sw1[o], s);
        s = fmaf(xv.y, sw1[32 + o], s);
        s = fmaf(xv.z, sw1[64 + o], s);
        s = fmaf(xv.w, sw1[96 + o], s);
        h1[o] = elu_f(s);
    }
    float h2[32];
    float d2 = 0.f;
#pragma unroll
    for (int o = 0; o < 32; ++o) {
        float s = sb2[o];
#pragma unroll
        for (int f = 0; f < 32; ++f) s = fmaf(h1[f], sw2[f * 32 + o], s);
        float v = elu_f(s);
        h2[o] = v;
        d2 = fmaf(v, v, d2);
    }
    float4* hp = reinterpret_cast<float4*>(hOut) + (size_t)node * 8;
#pragma unroll
    for (int j = 0; j < 8; ++j)
        hp[j] = make_float4(h2[4 * j], h2[4 * j + 1], h2[4 * j + 2], h2[4 * j + 3]);
    d2Out[node] = d2;
    pack_node(node, h2, hbf, til, d2b);
}

// sorted-ascending chain insert into top[KPW]
#define CHAIN14(nk_) do { \
    unsigned nk = (nk_); \
    _Pragma("unroll") \
    for (int jj = 0; jj < KPW; ++jj) { \
        unsigned tj = top[jj]; \
        unsigned lo = nk < tj ? nk : tj; \
        unsigned hi = nk < tj ? tj : nk; \
        top[jj] = lo; nk = hi; \
    } \
} while (0)

// list index for (query q, list li): wave (qt=q>>4, par=li>>2), lane (li&3)*16+(q&15)
#define LBASE(q, li) \
    (((((q) >> 4) * 2 + ((li) >> 2)) * 64 + ((li) & 3) * 16 + ((q) & 15)))

// ------------- MFMA kNN scan + parallel rank-to-pool -------------
// 512 blocks x 512 threads; block = 64 queries, 8 waves = 4 query tiles x 2
// cand-tile parities. Scan is barrier-free; A-fragments stream global(L2)->
// register; whole-graph d2 (16KB) staged to LDS once. Selection keys are raw
// MFMA acc bits; accept path branchless/exec-free; per-lane sorted top-14 via
// 16-deep stacks. Pool formation: ALL 512 threads (thread = (query, list))
// rank-select the smallest KM of each query's 112 keys — replaces the R9
// wave-0 serial merge (~37us at ~0% VALU; this is ~5-9us across 8 waves).
// Keys are globally unique (id bits) -> ranks unique -> pool set identical
// to the serial merge's top-32.
__global__ __launch_bounds__(512, 4) void k_scan(
    const unsigned short* __restrict__ til,
    const unsigned short* __restrict__ hbf,
    const float* __restrict__ d2b,
    unsigned short* __restrict__ mgs)
{
    __shared__ __align__(16) unsigned char smem[49152];
    constexpr int SD2 = 0;        // 16KB whole-graph bf16-consistent d2
    constexpr int STK = 16384;    // 8 waves x 4096B pending stacks (16 deep)
    constexpr int LST = 16384;    // sorted lists (reuse stacks after drain)

    const int tid = threadIdx.x;
    const int lane = tid & 63;
    const int wid = __builtin_amdgcn_readfirstlane(tid >> 6);
    const int qt = wid >> 1;
    const int par = wid & 1;
    const int bid = blockIdx.x;
    const int g = bid >> 6;
    const int gbase = g << 12;
    const int blockq = (bid & 63) * NBQ;
    const int qnode = gbase + blockq + qt * 16 + (lane & 15);
    const int rg = (lane >> 4) * 4;   // candidate row group base within tile

    // stage whole-graph d2 (4096 floats) once: 2 passes x 8 waves x 1KB
    gload_lds16(d2b + gbase + wid * 256 + lane * 4, smem + SD2 + wid * 1024);
    gload_lds16(d2b + gbase + 2048 + wid * 256 + lane * 4,
                smem + SD2 + 8192 + wid * 1024);

    // B fragment: query (lane&15) of this wave's tile, k-slice (lane>>4)*8..+8
    s16x8_t bfrag = *reinterpret_cast<const s16x8_t*>(
        hbf + (size_t)qnode * 32 + (lane >> 4) * 8);
    const float qd2 = d2b[qnode];
    const float nqd2h = -0.5f * qd2;

    unsigned top[KPW];
#pragma unroll
    for (int j = 0; j < KPW; ++j) top[j] = 0xFFFFFFFFu;
    unsigned thresh = 0xFFFFFFFFu;
    int pcnt = 0;

    // this wave's A-fragment stream base: tiles {par, par+2, par+4, par+6}
    const char* gtw = (const char*)til + (size_t)g * 262144
                    + (size_t)par * 1024 + (size_t)lane * 16;
    const float* d2s = reinterpret_cast<const float*>(smem + SD2);
    // per-lane element pointer into this wave's stack: slot j at stkl[j*64]
    unsigned* stkl = reinterpret_cast<unsigned*>(smem + STK + wid * 4096) + lane;

    __syncthreads();   // d2 staged

    // prologue: prefetch chunk 0 A-fragments into registers
    s16x8_t af[4];
#pragma unroll
    for (int i = 0; i < 4; ++i)
        af[i] = *reinterpret_cast<const s16x8_t*>(gtw + i * 2048);

    for (int c = 0; c < 32; ++c) {
        s16x8_t an[4];
        if (c < 31) {
#pragma unroll
            for (int i = 0; i < 4; ++i)
                an[i] = *reinterpret_cast<const s16x8_t*>(
                    gtw + (size_t)(c + 1) * 8192 + i * 2048);
        } else {
#pragma unroll
            for (int i = 0; i < 4; ++i) an[i] = af[i];
        }
        // candidate d2 for this chunk's 4 tiles (LDS, broadcast within 16 lanes)
        f32x4_t cv[4];
#pragma unroll
        for (int i = 0; i < 4; ++i)
            cv[i] = *reinterpret_cast<const f32x4_t*>(
                d2s + c * 128 + (i * 2 + par) * 16 + rg);
#pragma unroll
        for (int i = 0; i < 4; ++i) {
            const int t = i * 2 + par;
            f32x4_t acc;
#pragma unroll
            for (int r = 0; r < 4; ++r) acc[r] = fmaf(-0.5f, cv[i][r], nqd2h);
            acc = __builtin_amdgcn_mfma_f32_16x16x32_bf16(af[i], bfrag, acc, 0, 0, 0);
            const int cid0 = c * CHK + t * 16 + rg;
#pragma unroll
            for (int r = 0; r < 4; ++r) {
                // acc = -(d/2) <= 0; unsigned-ascending bit pattern == ascending d.
                unsigned key = (__float_as_uint(acc[r]) & 0xFFFFF000u)
                             | (unsigned)(cid0 + r);
                // branchless, exec-free accept
                stkl[pcnt * 64] = key;
                pcnt += (key < thresh) ? 1 : 0;
            }
            if (__any(pcnt >= TRIG)) {
#pragma unroll 1
                for (int j = 0; j < STKD; ++j) {
                    if (!__any(pcnt > j)) break;
                    unsigned kk = stkl[j * 64];                   // uncond read
                    unsigned k = (j < pcnt) ? kk : 0xFFFFFFFFu;   // select
                    CHAIN14(k);
                }
                pcnt = 0;
                thresh = top[KPW - 1];
            }
        }
#pragma unroll
        for (int i = 0; i < 4; ++i) af[i] = an[i];
    }
    // final drain
#pragma unroll 1
    for (int j = 0; j < STKD; ++j) {
        if (!__any(pcnt > j)) break;
        unsigned kk = stkl[j * 64];
        unsigned k = (j < pcnt) ? kk : 0xFFFFFFFFu;
        CHAIN14(k);
    }
    __syncthreads();   // all drains done before list region overwrites stacks

    // dump sorted lists
    unsigned* lst = reinterpret_cast<unsigned*>(smem + LST);
#pragma unroll
    for (int j = 0; j < KPW; ++j) lst[(wid * 64 + lane) * KPW + j] = top[j];
    __syncthreads();

    // parallel rank-to-pool: thread (q = tid>>3, li = tid&7). rank of my key j
    // = j (own sorted list) + sum over 7 peer lists of #{smaller}. Unique keys
    // -> unique ranks -> exactly KM keys with rank < KM.
    {
        const int q  = tid >> 3;
        const int li = tid & 7;
        const unsigned* myl = lst + LBASE(q, li) * KPW;
        unsigned mine[KPW];
        int rk[KPW];
#pragma unroll
        for (int j = 0; j < KPW; ++j) { mine[j] = myl[j]; rk[j] = j; }
        const unsigned myMax = mine[KPW - 1];
#pragma unroll 1
        for (int u = 1; u < 8; ++u) {
            const int lj = (li + u) & 7;
            const unsigned* pl = lst + LBASE(q, lj) * KPW;
#pragma unroll 1
            for (int k = 0; k < KPW; ++k) {
                unsigned pk = pl[k];
                if (pk >= myMax) break;   // sorted peer: no further contributions
#pragma unroll
                for (int j = 0; j < KPW; ++j) rk[j] += (pk < mine[j]) ? 1 : 0;
            }
        }
        unsigned short* mrow = mgs + (size_t)(gbase + blockq + q) * 32;
#pragma unroll
        for (int j = 0; j < KPW; ++j)
            if (rk[j] < KM) mrow[rk[j]] = (unsigned short)(mine[j] & 0xFFFu);
    }
}

// ------------- refine: exact top-24 from the KM pool + A/Bv precompute -------------
// 2048 blocks x 128 threads, 16 queries/block, one barrier (weight staging).
// The 8 threads of a query are contiguous lanes -> P3 rank-select runs on
// __shfl_xor exchanges (no LDS, no barriers): rank_i = #{(d_j,slot_j) <
// (d_i,slot_i)} over the 32-pool; ranks unique, the 24 smallest win.
__global__ __launch_bounds__(128) void k_refine(
    const unsigned short* __restrict__ mgs,
    const float* __restrict__ hf,
    const float* __restrict__ d2x,
    const float* __restrict__ cw, const float* __restrict__ cb,
    int* __restrict__ idxOut,
    float* __restrict__ Abuf, float* __restrict__ Bbuf)
{
    __shared__ float sw[2048];
    __shared__ float sb[32];

    const int tid = threadIdx.x;
    const int bid = blockIdx.x;
    const int g = bid >> 8;
    const int gbase = g << 12;
    const int blockq = (bid & 255) * 16;

    for (int i = tid; i < 2048; i += 128) sw[i] = cw[i];
    if (tid < 32) sb[tid] = cb[tid];
    __syncthreads();   // the only barrier

    const int q  = tid >> 3;        // 0..15
    const int s0 = tid & 7;
    const int qn = gbase + blockq + q;

    // q row (reused by P2 and A/B)
    const float4* qp = reinterpret_cast<const float4*>(hf) + (size_t)qn * 8;
    float4 qf[8];
#pragma unroll
    for (int j = 0; j < 8; ++j) qf[j] = qp[j];
    const float qd2e = d2x[qn];

    // P2: exact fp32 distances (8 threads/query, 4 cands each: s0+8ss)
    int cids[4];
    float d[4];
#pragma unroll
    for (int ss = 0; ss < 4; ++ss) {
        const int s = s0 + ss * 8;
        const int cid = (int)mgs[(size_t)qn * 32 + s];
        cids[ss] = cid;
        const int cn = gbase + cid;
        const float4* cp = reinterpret_cast<const float4*>(hf) + (size_t)cn * 8;
        float ax = 0.f, ay = 0.f, az = 0.f, aw = 0.f;
#pragma unroll
        for (int jj = 0; jj < 8; ++jj) {
            float4 cc = cp[jj];
            ax = fmaf(qf[jj].x, cc.x, ax);
            ay = fmaf(qf[jj].y, cc.y, ay);
            az = fmaf(qf[jj].z, cc.z, az);
            aw = fmaf(qf[jj].w, cc.w, aw);
        }
        float dot = (ax + ay) + (az + aw);
        d[ss] = fmaf(-2.f, dot, qd2e + d2x[cn]);
    }

    // P3: shfl rank-select across the query's 8 lanes (slots = lane-part + 8*ss)
    {
        int rk[4];
        // self pairs (same lane): tiebreak slot j<i
#pragma unroll
        for (int i = 0; i < 4; ++i) {
            int r = 0;
#pragma unroll
            for (int j = 0; j < 4; ++j) {
                if (j != i)
                    r += (d[j] < d[i] || (d[j] == d[i] && j < i)) ? 1 : 0;
            }
            rk[i] = r;
        }
#pragma unroll
        for (int t = 1; t < 8; ++t) {
            float pd[4];
#pragma unroll
            for (int ss = 0; ss < 4; ++ss) pd[ss] = __shfl_xor(d[ss], t);
            const int ps0 = s0 ^ t;
#pragma unroll
            for (int i = 0; i < 4; ++i) {
                const int mys = s0 + 8 * i;
#pragma unroll
                for (int ss = 0; ss < 4; ++ss) {
                    const int pss = ps0 + 8 * ss;
                    rk[i] += (pd[ss] < d[i] ||
                              (pd[ss] == d[i] && pss < mys)) ? 1 : 0;
                }
            }
        }
        int* o = idxOut + (size_t)qn * KNN;
#pragma unroll
        for (int i = 0; i < 4; ++i)
            if (rk[i] < KNN) o[rk[i]] = cids[i];
    }

    // A/B precompute: A = h@(W1-W2)+b, Bv = h@W2 (h row already in qf regs)
    {
        const int o0 = s0 * 4;
        float hreg[32];
#pragma unroll
        for (int j = 0; j < 8; ++j) {
            hreg[4 * j]     = qf[j].x; hreg[4 * j + 1] = qf[j].y;
            hreg[4 * j + 2] = qf[j].z; hreg[4 * j + 3] = qf[j].w;
        }
        float4 s1 = make_float4(0.f, 0.f, 0.f, 0.f);
        float4 s2 = make_float4(0.f, 0.f, 0.f, 0.f);
#pragma unroll
        for (int f = 0; f < 32; ++f) {
            float hv = hreg[f];
            float4 wa = *reinterpret_cast<const float4*>(sw + f * 32 + o0);
            float4 wb = *reinterpret_cast<const float4*>(sw + (32 + f) * 32 + o0);
            s1.x = fmaf(hv, wa.x, s1.x); s1.y = fmaf(hv, wa.y, s1.y);
            s1.z = fmaf(hv, wa.z, s1.z); s1.w = fmaf(hv, wa.w, s1.w);
            s2.x = fmaf(hv, wb.x, s2.x); s2.y = fmaf(hv, wb.y, s2.y);
            s2.z = fmaf(hv, wb.z, s2.z); s2.w = fmaf(hv, wb.w, s2.w);
        }
        float4 bv = *reinterpret_cast<const float4*>(sb + o0);
        float4 av = make_float4(s1.x - s2.x + bv.x, s1.y - s2.y + bv.y,
                                s1.z - s2.z + bv.z, s1.w - s2.w + bv.w);
        *reinterpret_cast<float4*>(Abuf + (size_t)qn * 32 + o0) = av;
        *reinterpret_cast<float4*>(Bbuf + (size_t)qn * 32 + o0) = s2;
    }
}

// ------------- aggregate: h_out = elu(A + max_k Bv[nbr]); LAST: fused output MLP -------------
template <bool LAST>
__global__ __launch_bounds__(128) void k_aggregate(
    const float* __restrict__ A, const float* __restrict__ Bv,
    const int* __restrict__ idx,
    float* __restrict__ hOut, float* __restrict__ d2Out,
    unsigned short* __restrict__ hbf, unsigned short* __restrict__ til,
    float* __restrict__ d2b,
    const float* __restrict__ w1, const float* __restrict__ b1,
    const float* __restrict__ w2, const float* __restrict__ b2,
    const float* __restrict__ w3, const float* __restrict__ b3,
    float* __restrict__ out)
{
    __shared__ float sw1[1024];
    __shared__ float sb1[32];
    __shared__ float sw2[512];
    __shared__ float sb2[16];
    __shared__ float sw3[128];
    __shared__ float sb3[8];
    int tid = threadIdx.x;
    if (LAST) {
        for (int i = tid; i < 1024; i += 128) sw1[i] = w1[i];
        for (int i = tid; i < 512; i += 128) sw2[i] = w2[i];
        sw3[tid] = w3[tid];                      // 128 threads, 128 entries
        if (tid < 32) sb1[tid] = b1[tid];
        if (tid >= 32 && tid < 48) sb2[tid - 32] = b2[tid - 32];
        if (tid >= 48 && tid < 56) sb3[tid - 48] = b3[tid - 48];
        __syncthreads();
    }

    int node = blockIdx.x * 128 + tid;
    int g = node >> 12;
    const int* ip = idx + (size_t)node * KNN;

    float4 m[8];
#pragma unroll
    for (int j = 0; j < 8; ++j) m[j] = make_float4(-1e30f, -1e30f, -1e30f, -1e30f);

    for (int k = 0; k < KNN; ++k) {
        int cand = (g << 12) + ip[k];
        const float4* bp = reinterpret_cast<const float4*>(Bv) + (size_t)cand * 8;
#pragma unroll
        for (int j = 0; j < 8; ++j) {
            float4 b = bp[j];
            m[j].x = fmaxf(m[j].x, b.x);
            m[j].y = fmaxf(m[j].y, b.y);
            m[j].z = fmaxf(m[j].z, b.z);
            m[j].w = fmaxf(m[j].w, b.w);
        }
    }
    const float4* ap = reinterpret_cast<const float4*>(A) + (size_t)node * 8;
    float hv[32];
    float d2 = 0.f;
#pragma unroll
    for (int j = 0; j < 8; ++j) {
        float4 a = ap[j];
        float4 v;
        v.x = elu_f(a.x + m[j].x);
        v.y = elu_f(a.y + m[j].y);
        v.z = elu_f(a.z + m[j].z);
        v.w = elu_f(a.w + m[j].w);
        d2 = fmaf(v.x, v.x, d2);
        d2 = fmaf(v.y, v.y, d2);
        d2 = fmaf(v.z, v.z, d2);
        d2 = fmaf(v.w, v.w, d2);
        hv[4 * j] = v.x; hv[4 * j + 1] = v.y; hv[4 * j + 2] = v.z; hv[4 * j + 3] = v.w;
    }

    if (!LAST) {
        float4* hp = reinterpret_cast<float4*>(hOut) + (size_t)node * 8;
#pragma unroll
        for (int j = 0; j < 8; ++j)
            hp[j] = make_float4(hv[4 * j], hv[4 * j + 1], hv[4 * j + 2], hv[4 * j + 3]);
        d2Out[node] = d2;
        pack_node(node, hv, hbf, til, d2b);
    } else {
        float o1[32];
#pragma unroll
        for (int o = 0; o < 32; ++o) {
            float s = sb1[o];
#pragma unroll
            for (int f = 0; f < 32; ++f) s = fmaf(hv[f], sw1[f * 32 + o], s);
            o1[o] = elu_f(s);
        }
        float o2[16];
#pragma unroll
        for (int o = 0; o < 16; ++o) {
            float s = sb2[o];
#pragma unroll
            for (int f = 0; f < 32; ++f) s = fmaf(o1[f], sw2[f * 16 + o], s);
            o2[o] = elu_f(s);
        }
        float o3[8];
#pragma unroll
        for (int o = 0; o < 8; ++o) {
            float s = sb3[o];
#pragma unroll
            for (int f = 0; f < 16; ++f) s = fmaf(o2[f], sw3[f * 8 + o], s);
            o3[o] = s;
        }
        float4* op = reinterpret_cast<float4*>(out) + (size_t)node * 2;
        op[0] = make_float4(o3[0], o3[1], o3[2], o3[3]);
        op[1] = make_float4(o3[4], o3[5], o3[6], o3[7]);
        out[(size_t)BN * 8 + node] = (float)(node >> 12);
    }
}

extern "C" void kernel_launch(void* const* d_in, const int* in_sizes, int n_in,
                              void* d_out, int out_size, void* d_ws, size_t ws_size,
                              hipStream_t stream)
{
    (void)in_sizes; (void)n_in; (void)out_size; (void)ws_size;
    const float* x      = (const float*)d_in[0];
    const float* enc_w1 = (const float*)d_in[2];
    const float* enc_b1 = (const float*)d_in[3];
    const float* enc_w2 = (const float*)d_in[4];
    const float* enc_b2 = (const float*)d_in[5];
    const float* conv_w[3] = { (const float*)d_in[6], (const float*)d_in[8], (const float*)d_in[10] };
    const float* conv_b[3] = { (const float*)d_in[7], (const float*)d_in[9], (const float*)d_in[11] };
    const float* out_w1 = (const float*)d_in[12];
    const float* out_b1 = (const float*)d_in[13];
    const float* out_w2 = (const float*)d_in[14];
    const float* out_b2 = (const float*)d_in[15];
    const float* out_w3 = (const float*)d_in[16];
    const float* out_b3 = (const float*)d_in[17];

    char* ws = (char*)d_ws;
    float*          hA   = (float*)(ws + 0);                  // 4 MB
    float*          hB   = (float*)(ws + 4194304);            // 4 MB
    unsigned short* hbfA = (unsigned short*)(ws + 8388608);   // 2 MB
    unsigned short* hbfB = (unsigned short*)(ws + 10485760);  // 2 MB
    unsigned short* tilA = (unsigned short*)(ws + 12582912);  // 2 MB
    unsigned short* tilB = (unsigned short*)(ws + 14680064);  // 2 MB
    float*          d2A  = (float*)(ws + 16777216);           // 128 KB
    float*          d2B  = (float*)(ws + 16908288);           // 128 KB
    float*          d2bA = (float*)(ws + 17039360);           // 128 KB
    float*          d2bB = (float*)(ws + 17170432);           // 128 KB
    int*            idx  = (int*)(ws + 17301504);             // 3.15 MB
    float*          Abuf = (float*)(ws + 20447232);           // 4 MB
    float*          Bbuf = (float*)(ws + 24641536);           // 4 MB

    k_encoder<<<256, 128, 0, stream>>>(x, enc_w1, enc_b1, enc_w2, enc_b2,
                                       hA, d2A, hbfA, tilA, d2bA);

    float* hin = hA;   float* d2in = d2A;   float* d2bin = d2bA;
    unsigned short* hbfin = hbfA; unsigned short* tilin = tilA;
    float* hout = hB;  float* d2out = d2B;  float* d2bout = d2bB;
    unsigned short* hbfout = hbfB; unsigned short* tilout = tilB;

    for (int l = 0; l < 3; ++l) {
        // pool ids (u16) alias the NEXT til buffer: dead until k_aggregate
        // writes it (stream-ordered after k_refine consumed the pool).
        unsigned short* mgs = tilout;
        k_scan<<<512, 512, 0, stream>>>(tilin, hbfin, d2bin, mgs);
        k_refine<<<2048, 128, 0, stream>>>(mgs, hin, d2in,
                                           conv_w[l], conv_b[l], idx, Abuf, Bbuf);
        if (l < 2) {
            k_aggregate<false><<<256, 128, 0, stream>>>(
                Abuf, Bbuf, idx, hout, d2out, hbfout, tilout, d2bout,
                nullptr, nullptr, nullptr, nullptr, nullptr, nullptr, nullptr);
        } else {
            k_aggregate<true><<<256, 128, 0, stream>>>(
                Abuf, Bbuf, idx, nullptr, nullptr, nullptr, nullptr, nullptr,
                out_w1, out_b1, out_w2, out_b2, out_w3, out_b3, (float*)d_out);
        }
        float* tf; unsigned short* ts;
        tf = hin; hin = hout; hout = tf;
        tf = d2in; d2in = d2out; d2out = tf;
        tf = d2bin; d2bin = d2bout; d2bout = tf;
        ts = hbfin; hbfin = hbfout; hbfout = ts;
        ts = tilin; tilin = tilout; tilout = ts;
    }
}

// Round 11
// 528.928 us; speedup vs baseline: 1.1337x; 1.0475x over previous
//
#include <hip/hip_runtime.h>
#include <cstddef>
#include <cstdint>

#define BN    32768   // B*N
#define NG    4096    // nodes per graph
#define KNN   24
#define KPW   14      // per-lane partial top over its 1/8 candidate subset
#define KM    32      // merged candidate pool for exact refine
#define CHK   128     // candidates per chunk
#define NBQ   64      // queries per knn block
#define STKD  16      // pending-stack depth per lane
#define TRIG  13      // flush trigger: pcnt<=12 pre-tile, +4 writes at slots<=15

typedef float f32x4_t __attribute__((ext_vector_type(4)));
typedef short s16x8_t __attribute__((ext_vector_type(8)));

__device__ __forceinline__ float elu_f(float x) {
    return x > 0.f ? x : expm1f(x);
}

__device__ __forceinline__ unsigned short f2bf(float f) {
    unsigned u = __float_as_uint(f);
    unsigned r = (u + 0x7FFFu + ((u >> 16) & 1u)) >> 16;   // RNE
    return (unsigned short)r;
}

__device__ __forceinline__ void gload_lds16(const void* g, void* l) {
    __builtin_amdgcn_global_load_lds(
        (const __attribute__((address_space(1))) unsigned*)g,
        (__attribute__((address_space(3))) unsigned*)l, 16, 0, 0);
}

// pack one node's 32 features: bf16 linear, bf16 MFMA-A-tiled, bf16-consistent d2
__device__ __forceinline__ void pack_node(int n, const float* hv,
    unsigned short* __restrict__ hbf, unsigned short* __restrict__ til,
    float* __restrict__ d2b)
{
    __align__(16) unsigned short us[32];
    float s = 0.f;
#pragma unroll
    for (int k = 0; k < 32; ++k) {
        us[k] = f2bf(hv[k]);
        float v = __uint_as_float(((unsigned)us[k]) << 16);
        s = fmaf(v, v, s);
    }
    d2b[n] = s;
    const uint4* up = reinterpret_cast<const uint4*>(us);
    uint4* lp = reinterpret_cast<uint4*>(hbf + (size_t)n * 32);
#pragma unroll
    for (int j = 0; j < 4; ++j) lp[j] = up[j];
    const int g = n >> 12, ln = n & 4095, tile = ln >> 4, c = ln & 15;
    unsigned short* tb = til + (size_t)g * 131072 + tile * 512 + c * 8;
#pragma unroll
    for (int kg = 0; kg < 4; ++kg)
        *reinterpret_cast<uint4*>(tb + kg * 128) = up[kg];
}

// ---------------- encoder: x[BN,4] -> h[BN,32] (+bf16 pack, d2, d2b) ----------------
// 256 blocks x 128 threads: one block per CU (all 256 CUs active)
__global__ __launch_bounds__(128) void k_encoder(
    const float* __restrict__ x,
    const float* __restrict__ w1, const float* __restrict__ b1,
    const float* __restrict__ w2, const float* __restrict__ b2,
    float* __restrict__ hOut, float* __restrict__ d2Out,
    unsigned short* __restrict__ hbf, unsigned short* __restrict__ til,
    float* __restrict__ d2b)
{
    __shared__ float sw1[4 * 32];
    __shared__ float sb1[32];
    __shared__ float sw2[32 * 32];
    __shared__ float sb2[32];
    int tid = threadIdx.x;
    sw1[tid] = w1[tid];                     // 128 threads, 128 entries
    if (tid < 32) sb1[tid] = b1[tid];
    for (int i = tid; i < 1024; i += 128) sw2[i] = w2[i];
    if (tid >= 32 && tid < 64) sb2[tid - 32] = b2[tid - 32];
    __syncthreads();

    int node = blockIdx.x * 128 + tid;
    float4 xv = reinterpret_cast<const float4*>(x)[node];

    float h1[32];
#pragma unroll
    for (int o = 0; o < 32; ++o) {
        float s = sb1[o];
        s = fmaf(xv.x, sw1[o], s);
        s = fmaf(xv.y, sw1[32 + o], s);
        s = fmaf(xv.z, sw1[64 + o], s);
        s = fmaf(xv.w, sw1[96 + o], s);
        h1[o] = elu_f(s);
    }
    float h2[32];
    float d2 = 0.f;
#pragma unroll
    for (int o = 0; o < 32; ++o) {
        float s = sb2[o];
#pragma unroll
        for (int f = 0; f < 32; ++f) s = fmaf(h1[f], sw2[f * 32 + o], s);
        float v = elu_f(s);
        h2[o] = v;
        d2 = fmaf(v, v, d2);
    }
    float4* hp = reinterpret_cast<float4*>(hOut) + (size_t)node * 8;
#pragma unroll
    for (int j = 0; j < 8; ++j)
        hp[j] = make_float4(h2[4 * j], h2[4 * j + 1], h2[4 * j + 2], h2[4 * j + 3]);
    d2Out[node] = d2;
    pack_node(node, h2, hbf, til, d2b);
}

// sorted-ascending chain insert into top[KPW]
#define CHAIN14(nk_) do { \
    unsigned nk = (nk_); \
    _Pragma("unroll") \
    for (int jj = 0; jj < KPW; ++jj) { \
        unsigned tj = top[jj]; \
        unsigned lo = nk < tj ? nk : tj; \
        unsigned hi = nk < tj ? tj : nk; \
        top[jj] = lo; nk = hi; \
    } \
} while (0)

// ------------- MFMA kNN scan + parallel rank-to-pool -------------
// 512 blocks x 512 threads; block = 64 queries, 8 waves = 4 query tiles x 2
// cand-tile parities. Scan is barrier-free; A-fragments stream global(L2)->
// register; whole-graph d2 (16KB) staged to LDS once. Selection keys are raw
// MFMA acc bits; accept path branchless/exec-free; per-lane sorted top-14 via
// 16-deep stacks. Pool formation (rank-to-pool v2): q-major stride-15 list
// layout (bank = 24q+15lj+k mod 32: 15*dlj==0 mod 8 iff dlj==0 -> all
// (q-class,lj) combos distinct banks, <=4-way vs v1's 8-way); identity
// mapping (my list = top[] regs, only 7x14 peer keys read, unconditional
// unrolled ds_reads -> ILP); 196 branchless cmp-adds/peer. Keys unique ->
// ranks unique -> pool set identical to the exact serial merge.
__global__ __launch_bounds__(512, 4) void k_scan(
    const unsigned short* __restrict__ til,
    const unsigned short* __restrict__ hbf,
    const float* __restrict__ d2b,
    unsigned short* __restrict__ mgs)
{
    __shared__ __align__(16) unsigned char smem[49152];
    constexpr int SD2 = 0;        // 16KB whole-graph bf16-consistent d2
    constexpr int STK = 16384;    // 8 waves x 4096B pending stacks (16 deep)
    constexpr int LST = 16384;    // lists (reuse stacks after drain): 7680 w

    const int tid = threadIdx.x;
    const int lane = tid & 63;
    const int wid = __builtin_amdgcn_readfirstlane(tid >> 6);
    const int qt = wid >> 1;
    const int par = wid & 1;
    const int bid = blockIdx.x;
    const int g = bid >> 6;
    const int gbase = g << 12;
    const int blockq = (bid & 63) * NBQ;
    const int qnode = gbase + blockq + qt * 16 + (lane & 15);
    const int rg = (lane >> 4) * 4;   // candidate row group base within tile

    // stage whole-graph d2 (4096 floats) once: 2 passes x 8 waves x 1KB
    gload_lds16(d2b + gbase + wid * 256 + lane * 4, smem + SD2 + wid * 1024);
    gload_lds16(d2b + gbase + 2048 + wid * 256 + lane * 4,
                smem + SD2 + 8192 + wid * 1024);

    // B fragment: query (lane&15) of this wave's tile, k-slice (lane>>4)*8..+8
    s16x8_t bfrag = *reinterpret_cast<const s16x8_t*>(
        hbf + (size_t)qnode * 32 + (lane >> 4) * 8);
    const float qd2 = d2b[qnode];
    const float nqd2h = -0.5f * qd2;

    unsigned top[KPW];
#pragma unroll
    for (int j = 0; j < KPW; ++j) top[j] = 0xFFFFFFFFu;
    unsigned thresh = 0xFFFFFFFFu;
    int pcnt = 0;

    // this wave's A-fragment stream base: tiles {par, par+2, par+4, par+6}
    const char* gtw = (const char*)til + (size_t)g * 262144
                    + (size_t)par * 1024 + (size_t)lane * 16;
    const float* d2s = reinterpret_cast<const float*>(smem + SD2);
    // per-lane element pointer into this wave's stack: slot j at stkl[j*64]
    unsigned* stkl = reinterpret_cast<unsigned*>(smem + STK + wid * 4096) + lane;

    __syncthreads();   // d2 staged

    // prologue: prefetch chunk 0 A-fragments into registers
    s16x8_t af[4];
#pragma unroll
    for (int i = 0; i < 4; ++i)
        af[i] = *reinterpret_cast<const s16x8_t*>(gtw + i * 2048);

    for (int c = 0; c < 32; ++c) {
        s16x8_t an[4];
        if (c < 31) {
#pragma unroll
            for (int i = 0; i < 4; ++i)
                an[i] = *reinterpret_cast<const s16x8_t*>(
                    gtw + (size_t)(c + 1) * 8192 + i * 2048);
        } else {
#pragma unroll
            for (int i = 0; i < 4; ++i) an[i] = af[i];
        }
        // candidate d2 for this chunk's 4 tiles (LDS, broadcast within 16 lanes)
        f32x4_t cv[4];
#pragma unroll
        for (int i = 0; i < 4; ++i)
            cv[i] = *reinterpret_cast<const f32x4_t*>(
                d2s + c * 128 + (i * 2 + par) * 16 + rg);
#pragma unroll
        for (int i = 0; i < 4; ++i) {
            const int t = i * 2 + par;
            f32x4_t acc;
#pragma unroll
            for (int r = 0; r < 4; ++r) acc[r] = fmaf(-0.5f, cv[i][r], nqd2h);
            acc = __builtin_amdgcn_mfma_f32_16x16x32_bf16(af[i], bfrag, acc, 0, 0, 0);
            const int cid0 = c * CHK + t * 16 + rg;
#pragma unroll
            for (int r = 0; r < 4; ++r) {
                // acc = -(d/2) <= 0; unsigned-ascending bit pattern == ascending d.
                unsigned key = (__float_as_uint(acc[r]) & 0xFFFFF000u)
                             | (unsigned)(cid0 + r);
                // branchless, exec-free accept
                stkl[pcnt * 64] = key;
                pcnt += (key < thresh) ? 1 : 0;
            }
            if (__any(pcnt >= TRIG)) {
#pragma unroll 1
                for (int j = 0; j < STKD; ++j) {
                    if (!__any(pcnt > j)) break;
                    unsigned kk = stkl[j * 64];                   // uncond read
                    unsigned k = (j < pcnt) ? kk : 0xFFFFFFFFu;   // select
                    CHAIN14(k);
                }
                pcnt = 0;
                thresh = top[KPW - 1];
            }
        }
#pragma unroll
        for (int i = 0; i < 4; ++i) af[i] = an[i];
    }
    // final drain
#pragma unroll 1
    for (int j = 0; j < STKD; ++j) {
        if (!__any(pcnt > j)) break;
        unsigned kk = stkl[j * 64];
        unsigned k = (j < pcnt) ? kk : 0xFFFFFFFFu;
        CHAIN14(k);
    }
    __syncthreads();   // all drains done before list region overwrites stacks

    // dump sorted lists: q-major, stride-15 (list (q,li) at lst + q*120 + li*15)
    unsigned* lst = reinterpret_cast<unsigned*>(smem + LST);
    const int q_d  = qt * 16 + (lane & 15);   // this thread's query
    const int li_d = par * 4 + (lane >> 4);   // this thread's list id
    {
        unsigned* myrow = lst + q_d * 120 + li_d * 15;
#pragma unroll
        for (int j = 0; j < KPW; ++j) myrow[j] = top[j];
    }
    __syncthreads();

    // parallel rank-to-pool (identity mapping: my list is top[] in regs).
    // rank(top[j]) = j + sum over 7 peers of #{peer key < top[j]}.
    {
        int rk[KPW];
#pragma unroll
        for (int j = 0; j < KPW; ++j) rk[j] = j;
        const unsigned* base = lst + q_d * 120;
#pragma unroll 1
        for (int u = 1; u < 8; ++u) {
            const unsigned* pl = base + ((li_d + u) & 7) * 15;
            unsigned pk[KPW];
#pragma unroll
            for (int k = 0; k < KPW; ++k) pk[k] = pl[k];   // independent reads
#pragma unroll
            for (int k = 0; k < KPW; ++k) {
#pragma unroll
                for (int j = 0; j < KPW; ++j)
                    rk[j] += (pk[k] < top[j]) ? 1 : 0;
            }
        }
        unsigned short* mrow = mgs + (size_t)(gbase + blockq + q_d) * 32;
#pragma unroll
        for (int j = 0; j < KPW; ++j)
            if (rk[j] < KM) mrow[rk[j]] = (unsigned short)(top[j] & 0xFFFu);
    }
}

// ------------- refine: exact top-24 from the KM pool + A/Bv precompute -------------
// 2048 blocks x 128 threads, 16 queries/block, one barrier (weight staging).
// The 8 threads of a query are contiguous lanes -> P3 rank-select runs on
// __shfl_xor exchanges (no LDS, no barriers): rank_i = #{(d_j,slot_j) <
// (d_i,slot_i)} over the 32-pool; ranks unique, the 24 smallest win.
__global__ __launch_bounds__(128) void k_refine(
    const unsigned short* __restrict__ mgs,
    const float* __restrict__ hf,
    const float* __restrict__ d2x,
    const float* __restrict__ cw, const float* __restrict__ cb,
    int* __restrict__ idxOut,
    float* __restrict__ Abuf, float* __restrict__ Bbuf)
{
    __shared__ float sw[2048];
    __shared__ float sb[32];

    const int tid = threadIdx.x;
    const int bid = blockIdx.x;
    const int g = bid >> 8;
    const int gbase = g << 12;
    const int blockq = (bid & 255) * 16;

    for (int i = tid; i < 2048; i += 128) sw[i] = cw[i];
    if (tid < 32) sb[tid] = cb[tid];
    __syncthreads();   // the only barrier

    const int q  = tid >> 3;        // 0..15
    const int s0 = tid & 7;
    const int qn = gbase + blockq + q;

    // q row (reused by P2 and A/B)
    const float4* qp = reinterpret_cast<const float4*>(hf) + (size_t)qn * 8;
    float4 qf[8];
#pragma unroll
    for (int j = 0; j < 8; ++j) qf[j] = qp[j];
    const float qd2e = d2x[qn];

    // P2: exact fp32 distances (8 threads/query, 4 cands each: s0+8ss)
    int cids[4];
    float d[4];
#pragma unroll
    for (int ss = 0; ss < 4; ++ss) {
        const int s = s0 + ss * 8;
        const int cid = (int)mgs[(size_t)qn * 32 + s];
        cids[ss] = cid;
        const int cn = gbase + cid;
        const float4* cp = reinterpret_cast<const float4*>(hf) + (size_t)cn * 8;
        float ax = 0.f, ay = 0.f, az = 0.f, aw = 0.f;
#pragma unroll
        for (int jj = 0; jj < 8; ++jj) {
            float4 cc = cp[jj];
            ax = fmaf(qf[jj].x, cc.x, ax);
            ay = fmaf(qf[jj].y, cc.y, ay);
            az = fmaf(qf[jj].z, cc.z, az);
            aw = fmaf(qf[jj].w, cc.w, aw);
        }
        float dot = (ax + ay) + (az + aw);
        d[ss] = fmaf(-2.f, dot, qd2e + d2x[cn]);
    }

    // P3: shfl rank-select across the query's 8 lanes (slots = lane-part + 8*ss)
    {
        int rk[4];
        // self pairs (same lane): tiebreak slot j<i
#pragma unroll
        for (int i = 0; i < 4; ++i) {
            int r = 0;
#pragma unroll
            for (int j = 0; j < 4; ++j) {
                if (j != i)
                    r += (d[j] < d[i] || (d[j] == d[i] && j < i)) ? 1 : 0;
            }
            rk[i] = r;
        }
#pragma unroll
        for (int t = 1; t < 8; ++t) {
            float pd[4];
#pragma unroll
            for (int ss = 0; ss < 4; ++ss) pd[ss] = __shfl_xor(d[ss], t);
            const int ps0 = s0 ^ t;
#pragma unroll
            for (int i = 0; i < 4; ++i) {
                const int mys = s0 + 8 * i;
#pragma unroll
                for (int ss = 0; ss < 4; ++ss) {
                    const int pss = ps0 + 8 * ss;
                    rk[i] += (pd[ss] < d[i] ||
                              (pd[ss] == d[i] && pss < mys)) ? 1 : 0;
                }
            }
        }
        int* o = idxOut + (size_t)qn * KNN;
#pragma unroll
        for (int i = 0; i < 4; ++i)
            if (rk[i] < KNN) o[rk[i]] = cids[i];
    }

    // A/B precompute: A = h@(W1-W2)+b, Bv = h@W2 (h row already in qf regs)
    {
        const int o0 = s0 * 4;
        float hreg[32];
#pragma unroll
        for (int j = 0; j < 8; ++j) {
            hreg[4 * j]     = qf[j].x; hreg[4 * j + 1] = qf[j].y;
            hreg[4 * j + 2] = qf[j].z; hreg[4 * j + 3] = qf[j].w;
        }
        float4 s1 = make_float4(0.f, 0.f, 0.f, 0.f);
        float4 s2 = make_float4(0.f, 0.f, 0.f, 0.f);
#pragma unroll
        for (int f = 0; f < 32; ++f) {
            float hv = hreg[f];
            float4 wa = *reinterpret_cast<const float4*>(sw + f * 32 + o0);
            float4 wb = *reinterpret_cast<const float4*>(sw + (32 + f) * 32 + o0);
            s1.x = fmaf(hv, wa.x, s1.x); s1.y = fmaf(hv, wa.y, s1.y);
            s1.z = fmaf(hv, wa.z, s1.z); s1.w = fmaf(hv, wa.w, s1.w);
            s2.x = fmaf(hv, wb.x, s2.x); s2.y = fmaf(hv, wb.y, s2.y);
            s2.z = fmaf(hv, wb.z, s2.z); s2.w = fmaf(hv, wb.w, s2.w);
        }
        float4 bv = *reinterpret_cast<const float4*>(sb + o0);
        float4 av = make_float4(s1.x - s2.x + bv.x, s1.y - s2.y + bv.y,
                                s1.z - s2.z + bv.z, s1.w - s2.w + bv.w);
        *reinterpret_cast<float4*>(Abuf + (size_t)qn * 32 + o0) = av;
        *reinterpret_cast<float4*>(Bbuf + (size_t)qn * 32 + o0) = s2;
    }
}

// ------------- aggregate: h_out = elu(A + max_k Bv[nbr]); LAST: fused output MLP -------------
template <bool LAST>
__global__ __launch_bounds__(128) void k_aggregate(
    const float* __restrict__ A, const float* __restrict__ Bv,
    const int* __restrict__ idx,
    float* __restrict__ hOut, float* __restrict__ d2Out,
    unsigned short* __restrict__ hbf, unsigned short* __restrict__ til,
    float* __restrict__ d2b,
    const float* __restrict__ w1, const float* __restrict__ b1,
    const float* __restrict__ w2, const float* __restrict__ b2,
    const float* __restrict__ w3, const float* __restrict__ b3,
    float* __restrict__ out)
{
    __shared__ float sw1[1024];
    __shared__ float sb1[32];
    __shared__ float sw2[512];
    __shared__ float sb2[16];
    __shared__ float sw3[128];
    __shared__ float sb3[8];
    int tid = threadIdx.x;
    if (LAST) {
        for (int i = tid; i < 1024; i += 128) sw1[i] = w1[i];
        for (int i = tid; i < 512; i += 128) sw2[i] = w2[i];
        sw3[tid] = w3[tid];                      // 128 threads, 128 entries
        if (tid < 32) sb1[tid] = b1[tid];
        if (tid >= 32 && tid < 48) sb2[tid - 32] = b2[tid - 32];
        if (tid >= 48 && tid < 56) sb3[tid - 48] = b3[tid - 48];
        __syncthreads();
    }

    int node = blockIdx.x * 128 + tid;
    int g = node >> 12;
    const int* ip = idx + (size_t)node * KNN;

    float4 m[8];
#pragma unroll
    for (int j = 0; j < 8; ++j) m[j] = make_float4(-1e30f, -1e30f, -1e30f, -1e30f);

    for (int k = 0; k < KNN; ++k) {
        int cand = (g << 12) + ip[k];
        const float4* bp = reinterpret_cast<const float4*>(Bv) + (size_t)cand * 8;
#pragma unroll
        for (int j = 0; j < 8; ++j) {
            float4 b = bp[j];
            m[j].x = fmaxf(m[j].x, b.x);
            m[j].y = fmaxf(m[j].y, b.y);
            m[j].z = fmaxf(m[j].z, b.z);
            m[j].w = fmaxf(m[j].w, b.w);
        }
    }
    const float4* ap = reinterpret_cast<const float4*>(A) + (size_t)node * 8;
    float hv[32];
    float d2 = 0.f;
#pragma unroll
    for (int j = 0; j < 8; ++j) {
        float4 a = ap[j];
        float4 v;
        v.x = elu_f(a.x + m[j].x);
        v.y = elu_f(a.y + m[j].y);
        v.z = elu_f(a.z + m[j].z);
        v.w = elu_f(a.w + m[j].w);
        d2 = fmaf(v.x, v.x, d2);
        d2 = fmaf(v.y, v.y, d2);
        d2 = fmaf(v.z, v.z, d2);
        d2 = fmaf(v.w, v.w, d2);
        hv[4 * j] = v.x; hv[4 * j + 1] = v.y; hv[4 * j + 2] = v.z; hv[4 * j + 3] = v.w;
    }

    if (!LAST) {
        float4* hp = reinterpret_cast<float4*>(hOut) + (size_t)node * 8;
#pragma unroll
        for (int j = 0; j < 8; ++j)
            hp[j] = make_float4(hv[4 * j], hv[4 * j + 1], hv[4 * j + 2], hv[4 * j + 3]);
        d2Out[node] = d2;
        pack_node(node, hv, hbf, til, d2b);
    } else {
        float o1[32];
#pragma unroll
        for (int o = 0; o < 32; ++o) {
            float s = sb1[o];
#pragma unroll
            for (int f = 0; f < 32; ++f) s = fmaf(hv[f], sw1[f * 32 + o], s);
            o1[o] = elu_f(s);
        }
        float o2[16];
#pragma unroll
        for (int o = 0; o < 16; ++o) {
            float s = sb2[o];
#pragma unroll
            for (int f = 0; f < 32; ++f) s = fmaf(o1[f], sw2[f * 16 + o], s);
            o2[o] = elu_f(s);
        }
        float o3[8];
#pragma unroll
        for (int o = 0; o < 8; ++o) {
            float s = sb3[o];
#pragma unroll
            for (int f = 0; f < 16; ++f) s = fmaf(o2[f], sw3[f * 8 + o], s);
            o3[o] = s;
        }
        float4* op = reinterpret_cast<float4*>(out) + (size_t)node * 2;
        op[0] = make_float4(o3[0], o3[1], o3[2], o3[3]);
        op[1] = make_float4(o3[4], o3[5], o3[6], o3[7]);
        out[(size_t)BN * 8 + node] = (float)(node >> 12);
    }
}

extern "C" void kernel_launch(void* const* d_in, const int* in_sizes, int n_in,
                              void* d_out, int out_size, void* d_ws, size_t ws_size,
                              hipStream_t stream)
{
    (void)in_sizes; (void)n_in; (void)out_size; (void)ws_size;
    const float* x      = (const float*)d_in[0];
    const float* enc_w1 = (const float*)d_in[2];
    const float* enc_b1 = (const float*)d_in[3];
    const float* enc_w2 = (const float*)d_in[4];
    const float* enc_b2 = (const float*)d_in[5];
    const float* conv_w[3] = { (const float*)d_in[6], (const float*)d_in[8], (const float*)d_in[10] };
    const float* conv_b[3] = { (const float*)d_in[7], (const float*)d_in[9], (const float*)d_in[11] };
    const float* out_w1 = (const float*)d_in[12];
    const float* out_b1 = (const float*)d_in[13];
    const float* out_w2 = (const float*)d_in[14];
    const float* out_b2 = (const float*)d_in[15];
    const float* out_w3 = (const float*)d_in[16];
    const float* out_b3 = (const float*)d_in[17];

    char* ws = (char*)d_ws;
    float*          hA   = (float*)(ws + 0);                  // 4 MB
    float*          hB   = (float*)(ws + 4194304);            // 4 MB
    unsigned short* hbfA = (unsigned short*)(ws + 8388608);   // 2 MB
    unsigned short* hbfB = (unsigned short*)(ws + 10485760);  // 2 MB
    unsigned short* tilA = (unsigned short*)(ws + 12582912);  // 2 MB
    unsigned short* tilB = (unsigned short*)(ws + 14680064);  // 2 MB
    float*          d2A  = (float*)(ws + 16777216);           // 128 KB
    float*          d2B  = (float*)(ws + 16908288);           // 128 KB
    float*          d2bA = (float*)(ws + 17039360);           // 128 KB
    float*          d2bB = (float*)(ws + 17170432);           // 128 KB
    int*            idx  = (int*)(ws + 17301504);             // 3.15 MB
    float*          Abuf = (float*)(ws + 20447232);           // 4 MB
    float*          Bbuf = (float*)(ws + 24641536);           // 4 MB

    k_encoder<<<256, 128, 0, stream>>>(x, enc_w1, enc_b1, enc_w2, enc_b2,
                                       hA, d2A, hbfA, tilA, d2bA);

    float* hin = hA;   float* d2in = d2A;   float* d2bin = d2bA;
    unsigned short* hbfin = hbfA; unsigned short* tilin = tilA;
    float* hout = hB;  float* d2out = d2B;  float* d2bout = d2bB;
    unsigned short* hbfout = hbfB; unsigned short* tilout = tilB;

    for (int l = 0; l < 3; ++l) {
        // pool ids (u16) alias the NEXT til buffer: dead until k_aggregate
        // writes it (stream-ordered after k_refine consumed the pool).
        unsigned short* mgs = tilout;
        k_scan<<<512, 512, 0, stream>>>(tilin, hbfin, d2bin, mgs);
        k_refine<<<2048, 128, 0, stream>>>(mgs, hin, d2in,
                                           conv_w[l], conv_b[l], idx, Abuf, Bbuf);
        if (l < 2) {
            k_aggregate<false><<<256, 128, 0, stream>>>(
                Abuf, Bbuf, idx, hout, d2out, hbfout, tilout, d2bout,
                nullptr, nullptr, nullptr, nullptr, nullptr, nullptr, nullptr);
        } else {
            k_aggregate<true><<<256, 128, 0, stream>>>(
                Abuf, Bbuf, idx, nullptr, nullptr, nullptr, nullptr, nullptr,
                out_w1, out_b1, out_w2, out_b2, out_w3, out_b3, (float*)d_out);
        }
        float* tf; unsigned short* ts;
        tf = hin; hin = hout; hout = tf;
        tf = d2in; d2in = d2out; d2out = tf;
        tf = d2bin; d2bin = d2bout; d2bout = tf;
        ts = hbfin; hbfin = hbfout; hbfout = ts;
        ts = tilin; tilin = tilout; tilout = ts;
    }
}

// Round 12
// 502.082 us; speedup vs baseline: 1.1943x; 1.0535x over previous
//
#include <hip/hip_runtime.h>
#include <cstddef>
#include <cstdint>

#define BN    32768   // B*N
#define NG    4096    // nodes per graph
#define KNN   24
#define KPW   14      // per-lane partial top over its 1/8 candidate subset
#define KM    32      // merged candidate pool for exact refine
#define CHK   128     // candidates per chunk
#define NBQ   64      // queries per knn block
#define STKD  16      // pending-stack depth per lane
#define TRIG  13      // flush trigger: pcnt<=12 pre-tile, +4 writes at slots<=15

typedef float f32x4_t __attribute__((ext_vector_type(4)));
typedef short s16x8_t __attribute__((ext_vector_type(8)));

__device__ __forceinline__ float elu_f(float x) {
    return x > 0.f ? x : expm1f(x);
}

__device__ __forceinline__ unsigned short f2bf(float f) {
    unsigned u = __float_as_uint(f);
    unsigned r = (u + 0x7FFFu + ((u >> 16) & 1u)) >> 16;   // RNE
    return (unsigned short)r;
}

__device__ __forceinline__ void gload_lds16(const void* g, void* l) {
    __builtin_amdgcn_global_load_lds(
        (const __attribute__((address_space(1))) unsigned*)g,
        (__attribute__((address_space(3))) unsigned*)l, 16, 0, 0);
}

// pack one node's 32 features: bf16 linear, bf16 MFMA-A-tiled, bf16-consistent d2
__device__ __forceinline__ void pack_node(int n, const float* hv,
    unsigned short* __restrict__ hbf, unsigned short* __restrict__ til,
    float* __restrict__ d2b)
{
    __align__(16) unsigned short us[32];
    float s = 0.f;
#pragma unroll
    for (int k = 0; k < 32; ++k) {
        us[k] = f2bf(hv[k]);
        float v = __uint_as_float(((unsigned)us[k]) << 16);
        s = fmaf(v, v, s);
    }
    d2b[n] = s;
    const uint4* up = reinterpret_cast<const uint4*>(us);
    uint4* lp = reinterpret_cast<uint4*>(hbf + (size_t)n * 32);
#pragma unroll
    for (int j = 0; j < 4; ++j) lp[j] = up[j];
    const int g = n >> 12, ln = n & 4095, tile = ln >> 4, c = ln & 15;
    unsigned short* tb = til + (size_t)g * 131072 + tile * 512 + c * 8;
#pragma unroll
    for (int kg = 0; kg < 4; ++kg)
        *reinterpret_cast<uint4*>(tb + kg * 128) = up[kg];
}

// ---------------- encoder: x[BN,4] -> h[BN,32] (+bf16 pack, d2, d2b) ----------------
// 256 blocks x 128 threads: one block per CU (all 256 CUs active)
__global__ __launch_bounds__(128) void k_encoder(
    const float* __restrict__ x,
    const float* __restrict__ w1, const float* __restrict__ b1,
    const float* __restrict__ w2, const float* __restrict__ b2,
    float* __restrict__ hOut, float* __restrict__ d2Out,
    unsigned short* __restrict__ hbf, unsigned short* __restrict__ til,
    float* __restrict__ d2b)
{
    __shared__ float sw1[4 * 32];
    __shared__ float sb1[32];
    __shared__ float sw2[32 * 32];
    __shared__ float sb2[32];
    int tid = threadIdx.x;
    sw1[tid] = w1[tid];                     // 128 threads, 128 entries
    if (tid < 32) sb1[tid] = b1[tid];
    for (int i = tid; i < 1024; i += 128) sw2[i] = w2[i];
    if (tid >= 32 && tid < 64) sb2[tid - 32] = b2[tid - 32];
    __syncthreads();

    int node = blockIdx.x * 128 + tid;
    float4 xv = reinterpret_cast<const float4*>(x)[node];

    float h1[32];
#pragma unroll
    for (int o = 0; o < 32; ++o) {
        float s = sb1[o];
        s = fmaf(xv.x, sw1[o], s);
        s = fmaf(xv.y, sw1[32 + o], s);
        s = fmaf(xv.z, sw1[64 + o], s);
        s = fmaf(xv.w, sw1[96 + o], s);
        h1[o] = elu_f(s);
    }
    float h2[32];
    float d2 = 0.f;
#pragma unroll
    for (int o = 0; o < 32; ++o) {
        float s = sb2[o];
#pragma unroll
        for (int f = 0; f < 32; ++f) s = fmaf(h1[f], sw2[f * 32 + o], s);
        float v = elu_f(s);
        h2[o] = v;
        d2 = fmaf(v, v, d2);
    }
    float4* hp = reinterpret_cast<float4*>(hOut) + (size_t)node * 8;
#pragma unroll
    for (int j = 0; j < 8; ++j)
        hp[j] = make_float4(h2[4 * j], h2[4 * j + 1], h2[4 * j + 2], h2[4 * j + 3]);
    d2Out[node] = d2;
    pack_node(node, h2, hbf, til, d2b);
}

// sorted-ascending chain insert into top[KPW]
#define CHAIN14(nk_) do { \
    unsigned nk = (nk_); \
    _Pragma("unroll") \
    for (int jj = 0; jj < KPW; ++jj) { \
        unsigned tj = top[jj]; \
        unsigned lo = nk < tj ? nk : tj; \
        unsigned hi = nk < tj ? tj : nk; \
        top[jj] = lo; nk = hi; \
    } \
} while (0)

// ------------- MFMA kNN scan + parallel rank-to-pool -------------
// 512 blocks x 512 threads; block = 64 queries, 8 waves = 4 query tiles x 2
// cand-tile parities. Scan is barrier-free; A-fragments stream global(L2)->
// register; whole-graph d2 (16KB) staged to LDS once. Selection keys are raw
// MFMA acc bits; accept path branchless/exec-free; per-lane sorted top-14 via
// 16-deep stacks. Pool formation (rank-to-pool v2): q-major stride-15 list
// layout; identity mapping (my list = top[] regs, only 7x14 peer keys read,
// unconditional unrolled ds_reads); 196 branchless cmp-adds/peer. Keys unique
// -> ranks unique -> pool set identical to the exact serial merge.
__global__ __launch_bounds__(512, 4) void k_scan(
    const unsigned short* __restrict__ til,
    const unsigned short* __restrict__ hbf,
    const float* __restrict__ d2b,
    unsigned short* __restrict__ mgs)
{
    __shared__ __align__(16) unsigned char smem[49152];
    constexpr int SD2 = 0;        // 16KB whole-graph bf16-consistent d2
    constexpr int STK = 16384;    // 8 waves x 4096B pending stacks (16 deep)
    constexpr int LST = 16384;    // lists (reuse stacks after drain): 7680 w

    const int tid = threadIdx.x;
    const int lane = tid & 63;
    const int wid = __builtin_amdgcn_readfirstlane(tid >> 6);
    const int qt = wid >> 1;
    const int par = wid & 1;
    const int bid = blockIdx.x;
    const int g = bid >> 6;
    const int gbase = g << 12;
    const int blockq = (bid & 63) * NBQ;
    const int qnode = gbase + blockq + qt * 16 + (lane & 15);
    const int rg = (lane >> 4) * 4;   // candidate row group base within tile

    // stage whole-graph d2 (4096 floats) once: 2 passes x 8 waves x 1KB
    gload_lds16(d2b + gbase + wid * 256 + lane * 4, smem + SD2 + wid * 1024);
    gload_lds16(d2b + gbase + 2048 + wid * 256 + lane * 4,
                smem + SD2 + 8192 + wid * 1024);

    // B fragment: query (lane&15) of this wave's tile, k-slice (lane>>4)*8..+8
    s16x8_t bfrag = *reinterpret_cast<const s16x8_t*>(
        hbf + (size_t)qnode * 32 + (lane >> 4) * 8);
    const float qd2 = d2b[qnode];
    const float nqd2h = -0.5f * qd2;

    unsigned top[KPW];
#pragma unroll
    for (int j = 0; j < KPW; ++j) top[j] = 0xFFFFFFFFu;
    unsigned thresh = 0xFFFFFFFFu;
    int pcnt = 0;

    // this wave's A-fragment stream base: tiles {par, par+2, par+4, par+6}
    const char* gtw = (const char*)til + (size_t)g * 262144
                    + (size_t)par * 1024 + (size_t)lane * 16;
    const float* d2s = reinterpret_cast<const float*>(smem + SD2);
    // per-lane element pointer into this wave's stack: slot j at stkl[j*64]
    unsigned* stkl = reinterpret_cast<unsigned*>(smem + STK + wid * 4096) + lane;

    __syncthreads();   // d2 staged

    // prologue: prefetch chunk 0 A-fragments into registers
    s16x8_t af[4];
#pragma unroll
    for (int i = 0; i < 4; ++i)
        af[i] = *reinterpret_cast<const s16x8_t*>(gtw + i * 2048);

    for (int c = 0; c < 32; ++c) {
        s16x8_t an[4];
        if (c < 31) {
#pragma unroll
            for (int i = 0; i < 4; ++i)
                an[i] = *reinterpret_cast<const s16x8_t*>(
                    gtw + (size_t)(c + 1) * 8192 + i * 2048);
        } else {
#pragma unroll
            for (int i = 0; i < 4; ++i) an[i] = af[i];
        }
        // candidate d2 for this chunk's 4 tiles (LDS, broadcast within 16 lanes)
        f32x4_t cv[4];
#pragma unroll
        for (int i = 0; i < 4; ++i)
            cv[i] = *reinterpret_cast<const f32x4_t*>(
                d2s + c * 128 + (i * 2 + par) * 16 + rg);
#pragma unroll
        for (int i = 0; i < 4; ++i) {
            const int t = i * 2 + par;
            f32x4_t acc;
#pragma unroll
            for (int r = 0; r < 4; ++r) acc[r] = fmaf(-0.5f, cv[i][r], nqd2h);
            acc = __builtin_amdgcn_mfma_f32_16x16x32_bf16(af[i], bfrag, acc, 0, 0, 0);
            const int cid0 = c * CHK + t * 16 + rg;
#pragma unroll
            for (int r = 0; r < 4; ++r) {
                // acc = -(d/2) <= 0; unsigned-ascending bit pattern == ascending d.
                unsigned key = (__float_as_uint(acc[r]) & 0xFFFFF000u)
                             | (unsigned)(cid0 + r);
                // branchless, exec-free accept
                stkl[pcnt * 64] = key;
                pcnt += (key < thresh) ? 1 : 0;
            }
            if (__any(pcnt >= TRIG)) {
#pragma unroll 1
                for (int j = 0; j < STKD; ++j) {
                    if (!__any(pcnt > j)) break;
                    unsigned kk = stkl[j * 64];                   // uncond read
                    unsigned k = (j < pcnt) ? kk : 0xFFFFFFFFu;   // select
                    CHAIN14(k);
                }
                pcnt = 0;
                thresh = top[KPW - 1];
            }
        }
#pragma unroll
        for (int i = 0; i < 4; ++i) af[i] = an[i];
    }
    // final drain
#pragma unroll 1
    for (int j = 0; j < STKD; ++j) {
        if (!__any(pcnt > j)) break;
        unsigned kk = stkl[j * 64];
        unsigned k = (j < pcnt) ? kk : 0xFFFFFFFFu;
        CHAIN14(k);
    }
    __syncthreads();   // all drains done before list region overwrites stacks

    // dump sorted lists: q-major, stride-15 (list (q,li) at lst + q*120 + li*15)
    unsigned* lst = reinterpret_cast<unsigned*>(smem + LST);
    const int q_d  = qt * 16 + (lane & 15);   // this thread's query
    const int li_d = par * 4 + (lane >> 4);   // this thread's list id
    {
        unsigned* myrow = lst + q_d * 120 + li_d * 15;
#pragma unroll
        for (int j = 0; j < KPW; ++j) myrow[j] = top[j];
    }
    __syncthreads();

    // parallel rank-to-pool (identity mapping: my list is top[] in regs).
    // rank(top[j]) = j + sum over 7 peers of #{peer key < top[j]}.
    {
        int rk[KPW];
#pragma unroll
        for (int j = 0; j < KPW; ++j) rk[j] = j;
        const unsigned* base = lst + q_d * 120;
#pragma unroll 1
        for (int u = 1; u < 8; ++u) {
            const unsigned* pl = base + ((li_d + u) & 7) * 15;
            unsigned pk[KPW];
#pragma unroll
            for (int k = 0; k < KPW; ++k) pk[k] = pl[k];   // independent reads
#pragma unroll
            for (int k = 0; k < KPW; ++k) {
#pragma unroll
                for (int j = 0; j < KPW; ++j)
                    rk[j] += (pk[k] < top[j]) ? 1 : 0;
            }
        }
        unsigned short* mrow = mgs + (size_t)(gbase + blockq + q_d) * 32;
#pragma unroll
        for (int j = 0; j < KPW; ++j)
            if (rk[j] < KM) mrow[rk[j]] = (unsigned short)(top[j] & 0xFFFu);
    }
}

// ------------- refine: exact top-24 from the KM pool + A/Bv precompute -------------
// 2048 blocks x 128 threads, 16 queries/block (8 lanes/query), one barrier.
// P2 is COOPERATIVE: per candidate, the query's 8 lanes load the row
// coalesced (8 x 16B = one 128B segment, vs R11's 44 uncoalesced requests
// per thread) and butterfly-reduce partial dots (__shfl_xor width=8) so every
// lane holds all 32 exact distances in statically-indexed registers. Rank-
// select is then lane-local (no cross-lane stage). A/B reads the full q row
// from a 2KB LDS stage (broadcast reads, conflict-free).
__global__ __launch_bounds__(128) void k_refine(
    const unsigned short* __restrict__ mgs,
    const float* __restrict__ hf,
    const float* __restrict__ d2x,
    const float* __restrict__ cw, const float* __restrict__ cb,
    int* __restrict__ idxOut,
    float* __restrict__ Abuf, float* __restrict__ Bbuf)
{
    __shared__ float sw[2048];
    __shared__ float sb[32];
    __shared__ __align__(16) float shq[16][32];   // block's 16 q rows

    const int tid = threadIdx.x;
    const int bid = blockIdx.x;
    const int g = bid >> 8;
    const int gbase = g << 12;
    const int blockq = (bid & 255) * 16;

    const int q  = tid >> 3;        // 0..15
    const int s0 = tid & 7;
    const int qn = gbase + blockq + q;

    // my 16B chunk of the q row (feeds P2 partial dots AND the LDS stage)
    const float4 qc = reinterpret_cast<const float4*>(hf)[(size_t)qn * 8 + s0];

    for (int i = tid; i < 2048; i += 128) sw[i] = cw[i];
    if (tid < 32) sb[tid] = cb[tid];
    *reinterpret_cast<float4*>(&shq[q][s0 * 4]) = qc;
    __syncthreads();   // the only barrier

    const float qd2e = d2x[qn];

    // P2: cooperative exact distances; all 32 land in per-lane registers
    float dall[32];
    float d_own[4];
    int cid_own[4];
#pragma unroll
    for (int i = 0; i < 4; ++i) { d_own[i] = 0.f; cid_own[i] = 0; }
#pragma unroll
    for (int s = 0; s < 32; ++s) {
        const int cid = (int)mgs[(size_t)qn * 32 + s];   // group-uniform load
        const int cn = gbase + cid;
        const float4 cc = reinterpret_cast<const float4*>(hf)[(size_t)cn * 8 + s0];
        float p = qc.x * cc.x;
        p = fmaf(qc.y, cc.y, p);
        p = fmaf(qc.z, cc.z, p);
        p = fmaf(qc.w, cc.w, p);
        p += __shfl_xor(p, 1, 8);
        p += __shfl_xor(p, 2, 8);
        p += __shfl_xor(p, 4, 8);   // all 8 lanes: full dot
        const float dv = fmaf(-2.f, p, qd2e + d2x[cn]);
        dall[s] = dv;
        // capture owned slots (s & 7 == s0) with static destination index
        const bool own = ((s & 7) == s0);
        d_own[s >> 3]   = own ? dv  : d_own[s >> 3];
        cid_own[s >> 3] = own ? cid : cid_own[s >> 3];
    }

    // P3: lane-local rank-select of owned cands (slots s0+8i); ranks unique
    {
        int* o = idxOut + (size_t)qn * KNN;
#pragma unroll
        for (int i = 0; i < 4; ++i) {
            const int mys = s0 + 8 * i;
            const float di = d_own[i];
            int rank = 0;
#pragma unroll
            for (int j = 0; j < 32; ++j)
                rank += (dall[j] < di || (dall[j] == di && j < mys)) ? 1 : 0;
            if (rank < KNN) o[rank] = cid_own[i];
        }
    }

    // A/B precompute: A = h@(W1-W2)+b, Bv = h@W2 (full q row from LDS stage)
    {
        const int o0 = s0 * 4;
        const float* hr = shq[q];
        float4 s1 = make_float4(0.f, 0.f, 0.f, 0.f);
        float4 s2 = make_float4(0.f, 0.f, 0.f, 0.f);
#pragma unroll
        for (int f = 0; f < 32; ++f) {
            float hv = hr[f];
            float4 wa = *reinterpret_cast<const float4*>(sw + f * 32 + o0);
            float4 wb = *reinterpret_cast<const float4*>(sw + (32 + f) * 32 + o0);
            s1.x = fmaf(hv, wa.x, s1.x); s1.y = fmaf(hv, wa.y, s1.y);
            s1.z = fmaf(hv, wa.z, s1.z); s1.w = fmaf(hv, wa.w, s1.w);
            s2.x = fmaf(hv, wb.x, s2.x); s2.y = fmaf(hv, wb.y, s2.y);
            s2.z = fmaf(hv, wb.z, s2.z); s2.w = fmaf(hv, wb.w, s2.w);
        }
        float4 bv = *reinterpret_cast<const float4*>(sb + o0);
        float4 av = make_float4(s1.x - s2.x + bv.x, s1.y - s2.y + bv.y,
                                s1.z - s2.z + bv.z, s1.w - s2.w + bv.w);
        *reinterpret_cast<float4*>(Abuf + (size_t)qn * 32 + o0) = av;
        *reinterpret_cast<float4*>(Bbuf + (size_t)qn * 32 + o0) = s2;
    }
}

// ------------- aggregate: h_out = elu(A + max_k Bv[nbr]); LAST: fused output MLP -------------
template <bool LAST>
__global__ __launch_bounds__(128) void k_aggregate(
    const float* __restrict__ A, const float* __restrict__ Bv,
    const int* __restrict__ idx,
    float* __restrict__ hOut, float* __restrict__ d2Out,
    unsigned short* __restrict__ hbf, unsigned short* __restrict__ til,
    float* __restrict__ d2b,
    const float* __restrict__ w1, const float* __restrict__ b1,
    const float* __restrict__ w2, const float* __restrict__ b2,
    const float* __restrict__ w3, const float* __restrict__ b3,
    float* __restrict__ out)
{
    __shared__ float sw1[1024];
    __shared__ float sb1[32];
    __shared__ float sw2[512];
    __shared__ float sb2[16];
    __shared__ float sw3[128];
    __shared__ float sb3[8];
    int tid = threadIdx.x;
    if (LAST) {
        for (int i = tid; i < 1024; i += 128) sw1[i] = w1[i];
        for (int i = tid; i < 512; i += 128) sw2[i] = w2[i];
        sw3[tid] = w3[tid];                      // 128 threads, 128 entries
        if (tid < 32) sb1[tid] = b1[tid];
        if (tid >= 32 && tid < 48) sb2[tid - 32] = b2[tid - 32];
        if (tid >= 48 && tid < 56) sb3[tid - 48] = b3[tid - 48];
        __syncthreads();
    }

    int node = blockIdx.x * 128 + tid;
    int g = node >> 12;
    const int* ip = idx + (size_t)node * KNN;

    float4 m[8];
#pragma unroll
    for (int j = 0; j < 8; ++j) m[j] = make_float4(-1e30f, -1e30f, -1e30f, -1e30f);

    for (int k = 0; k < KNN; ++k) {
        int cand = (g << 12) + ip[k];
        const float4* bp = reinterpret_cast<const float4*>(Bv) + (size_t)cand * 8;
#pragma unroll
        for (int j = 0; j < 8; ++j) {
            float4 b = bp[j];
            m[j].x = fmaxf(m[j].x, b.x);
            m[j].y = fmaxf(m[j].y, b.y);
            m[j].z = fmaxf(m[j].z, b.z);
            m[j].w = fmaxf(m[j].w, b.w);
        }
    }
    const float4* ap = reinterpret_cast<const float4*>(A) + (size_t)node * 8;
    float hv[32];
    float d2 = 0.f;
#pragma unroll
    for (int j = 0; j < 8; ++j) {
        float4 a = ap[j];
        float4 v;
        v.x = elu_f(a.x + m[j].x);
        v.y = elu_f(a.y + m[j].y);
        v.z = elu_f(a.z + m[j].z);
        v.w = elu_f(a.w + m[j].w);
        d2 = fmaf(v.x, v.x, d2);
        d2 = fmaf(v.y, v.y, d2);
        d2 = fmaf(v.z, v.z, d2);
        d2 = fmaf(v.w, v.w, d2);
        hv[4 * j] = v.x; hv[4 * j + 1] = v.y; hv[4 * j + 2] = v.z; hv[4 * j + 3] = v.w;
    }

    if (!LAST) {
        float4* hp = reinterpret_cast<float4*>(hOut) + (size_t)node * 8;
#pragma unroll
        for (int j = 0; j < 8; ++j)
            hp[j] = make_float4(hv[4 * j], hv[4 * j + 1], hv[4 * j + 2], hv[4 * j + 3]);
        d2Out[node] = d2;
        pack_node(node, hv, hbf, til, d2b);
    } else {
        float o1[32];
#pragma unroll
        for (int o = 0; o < 32; ++o) {
            float s = sb1[o];
#pragma unroll
            for (int f = 0; f < 32; ++f) s = fmaf(hv[f], sw1[f * 32 + o], s);
            o1[o] = elu_f(s);
        }
        float o2[16];
#pragma unroll
        for (int o = 0; o < 16; ++o) {
            float s = sb2[o];
#pragma unroll
            for (int f = 0; f < 32; ++f) s = fmaf(o1[f], sw2[f * 16 + o], s);
            o2[o] = elu_f(s);
        }
        float o3[8];
#pragma unroll
        for (int o = 0; o < 8; ++o) {
            float s = sb3[o];
#pragma unroll
            for (int f = 0; f < 16; ++f) s = fmaf(o2[f], sw3[f * 8 + o], s);
            o3[o] = s;
        }
        float4* op = reinterpret_cast<float4*>(out) + (size_t)node * 2;
        op[0] = make_float4(o3[0], o3[1], o3[2], o3[3]);
        op[1] = make_float4(o3[4], o3[5], o3[6], o3[7]);
        out[(size_t)BN * 8 + node] = (float)(node >> 12);
    }
}

extern "C" void kernel_launch(void* const* d_in, const int* in_sizes, int n_in,
                              void* d_out, int out_size, void* d_ws, size_t ws_size,
                              hipStream_t stream)
{
    (void)in_sizes; (void)n_in; (void)out_size; (void)ws_size;
    const float* x      = (const float*)d_in[0];
    const float* enc_w1 = (const float*)d_in[2];
    const float* enc_b1 = (const float*)d_in[3];
    const float* enc_w2 = (const float*)d_in[4];
    const float* enc_b2 = (const float*)d_in[5];
    const float* conv_w[3] = { (const float*)d_in[6], (const float*)d_in[8], (const float*)d_in[10] };
    const float* conv_b[3] = { (const float*)d_in[7], (const float*)d_in[9], (const float*)d_in[11] };
    const float* out_w1 = (const float*)d_in[12];
    const float* out_b1 = (const float*)d_in[13];
    const float* out_w2 = (const float*)d_in[14];
    const float* out_b2 = (const float*)d_in[15];
    const float* out_w3 = (const float*)d_in[16];
    const float* out_b3 = (const float*)d_in[17];

    char* ws = (char*)d_ws;
    float*          hA   = (float*)(ws + 0);                  // 4 MB
    float*          hB   = (float*)(ws + 4194304);            // 4 MB
    unsigned short* hbfA = (unsigned short*)(ws + 8388608);   // 2 MB
    unsigned short* hbfB = (unsigned short*)(ws + 10485760);  // 2 MB
    unsigned short* tilA = (unsigned short*)(ws + 12582912);  // 2 MB
    unsigned short* tilB = (unsigned short*)(ws + 14680064);  // 2 MB
    float*          d2A  = (float*)(ws + 16777216);           // 128 KB
    float*          d2B  = (float*)(ws + 16908288);           // 128 KB
    float*          d2bA = (float*)(ws + 17039360);           // 128 KB
    float*          d2bB = (float*)(ws + 17170432);           // 128 KB
    int*            idx  = (int*)(ws + 17301504);             // 3.15 MB
    float*          Abuf = (float*)(ws + 20447232);           // 4 MB
    float*          Bbuf = (float*)(ws + 24641536);           // 4 MB

    k_encoder<<<256, 128, 0, stream>>>(x, enc_w1, enc_b1, enc_w2, enc_b2,
                                       hA, d2A, hbfA, tilA, d2bA);

    float* hin = hA;   float* d2in = d2A;   float* d2bin = d2bA;
    unsigned short* hbfin = hbfA; unsigned short* tilin = tilA;
    float* hout = hB;  float* d2out = d2B;  float* d2bout = d2bB;
    unsigned short* hbfout = hbfB; unsigned short* tilout = tilB;

    for (int l = 0; l < 3; ++l) {
        // pool ids (u16) alias the NEXT til buffer: dead until k_aggregate
        // writes it (stream-ordered after k_refine consumed the pool).
        unsigned short* mgs = tilout;
        k_scan<<<512, 512, 0, stream>>>(tilin, hbfin, d2bin, mgs);
        k_refine<<<2048, 128, 0, stream>>>(mgs, hin, d2in,
                                           conv_w[l], conv_b[l], idx, Abuf, Bbuf);
        if (l < 2) {
            k_aggregate<false><<<256, 128, 0, stream>>>(
                Abuf, Bbuf, idx, hout, d2out, hbfout, tilout, d2bout,
                nullptr, nullptr, nullptr, nullptr, nullptr, nullptr, nullptr);
        } else {
            k_aggregate<true><<<256, 128, 0, stream>>>(
                Abuf, Bbuf, idx, nullptr, nullptr, nullptr, nullptr, nullptr,
                out_w1, out_b1, out_w2, out_b2, out_w3, out_b3, (float*)d_out);
        }
        float* tf; unsigned short* ts;
        tf = hin; hin = hout; hout = tf;
        tf = d2in; d2in = d2out; d2out = tf;
        tf = d2bin; d2bin = d2bout; d2bout = tf;
        ts = hbfin; hbfin = hbfout; hbfout = ts;
        ts = tilin; tilin = tilout; tilout = ts;
    }
}